// Round 1
// baseline (724.577 us; speedup 1.0000x reference)
//
#include <hip/hip_runtime.h>
#include <hip/hip_bf16.h>

#define B_ 2
#define T_ 2048
#define D_ 2048
#define H_ 16
#define HD_ 128
#define M_ 4096

typedef __attribute__((ext_vector_type(8))) short short8;
typedef __attribute__((ext_vector_type(8))) __bf16 bf16x8;
typedef __attribute__((ext_vector_type(4))) float f32x4;

__device__ __forceinline__ short f2bf(float f) {
  unsigned u = __builtin_bit_cast(unsigned, f);
  u += 0x7fffu + ((u >> 16) & 1u);
  return (short)(u >> 16);
}

__device__ __forceinline__ void gl_lds16(const void* g, void* l) {
  __builtin_amdgcn_global_load_lds(
      (const __attribute__((address_space(1))) unsigned int*)g,
      (__attribute__((address_space(3))) unsigned int*)l, 16, 0, 0);
}

__device__ __forceinline__ f32x4 mfma_bf16(short8 a, short8 b, f32x4 c) {
  return __builtin_amdgcn_mfma_f32_16x16x32_bf16(
      __builtin_bit_cast(bf16x8, a), __builtin_bit_cast(bf16x8, b), c, 0, 0, 0);
}

// ---------------- cast x -> bf16 ----------------
__global__ void cast_f32_bf16(const float* __restrict__ in, short* __restrict__ out, int n4) {
  int i = blockIdx.x * blockDim.x + threadIdx.x;
  int stride = gridDim.x * blockDim.x;
  for (; i < n4; i += stride) {
    float4 v = ((const float4*)in)[i];
    short4 s;
    s.x = f2bf(v.x); s.y = f2bf(v.y); s.z = f2bf(v.z); s.w = f2bf(v.w);
    ((short4*)out)[i] = s;
  }
}

// ---------------- W (K,N) f32 -> Wt (N,K) bf16 ----------------
__global__ void transpose_cast_w(const float* __restrict__ W, short* __restrict__ Wt) {
  __shared__ float t[32][33];
  int n0 = blockIdx.x * 32, k0 = blockIdx.y * 32;
  int tx = threadIdx.x, ty = threadIdx.y;
#pragma unroll
  for (int j = 0; j < 4; ++j)
    t[ty + j * 8][tx] = W[(size_t)(k0 + ty + j * 8) * D_ + n0 + tx];
  __syncthreads();
#pragma unroll
  for (int j = 0; j < 4; ++j)
    Wt[(size_t)(n0 + ty + j * 8) * D_ + k0 + tx] = f2bf(t[tx][ty + j * 8]);
}

// ---------------- v (bh,T,HD) bf16 -> vt (bh,HD,T) bf16 ----------------
__global__ void transpose_v(const short* __restrict__ vb, short* __restrict__ vtb) {
  __shared__ short t[32][33];
  int bh = blockIdx.z;
  int t0 = blockIdx.x * 32, h0 = blockIdx.y * 32;
  int tx = threadIdx.x, ty = threadIdx.y;
  const short* src = vb + (size_t)bh * T_ * HD_;
  short* dst = vtb + (size_t)bh * HD_ * T_;
#pragma unroll
  for (int j = 0; j < 4; ++j)
    t[ty + j * 8][tx] = src[(size_t)(t0 + ty + j * 8) * HD_ + h0 + tx];
  __syncthreads();
#pragma unroll
  for (int j = 0; j < 4; ++j)
    dst[(size_t)(h0 + ty + j * 8) * T_ + t0 + tx] = t[tx][ty + j * 8];
}

// ---------------- GEMM: C(M,N) = A(M,K)bf16 * Bt(N,K)bf16 + bias ----------------
// MODE 0: bf16 -> obf split-head [b][h][t][hd]
// MODE 1: MODE0 + fp32 -> of32 split-head (k/v outputs)
// MODE 3: fp32 -> of32 row-major (M,N)
template <int MODE>
__global__ __launch_bounds__(256) void gemm_bt(
    const short* __restrict__ A, const short* __restrict__ Bt,
    const float* __restrict__ bias, short* __restrict__ obf,
    float* __restrict__ of32) {
  __shared__ __attribute__((aligned(16))) short Alds[128 * 32];
  __shared__ __attribute__((aligned(16))) short Blds[128 * 32];
  const int K = D_;
  int tid = threadIdx.x;
  int m0 = blockIdx.y * 128, n0 = blockIdx.x * 128;
  int lane = tid & 63, w = tid >> 6, wr = w >> 1, wc = w & 1;
  int lr = lane & 15, ls = lane >> 4;
  f32x4 acc[4][4] = {};

  const short* ag = A + (size_t)(m0 + (tid >> 2)) * K + (tid & 3) * 8;
  const short* bg = Bt + (size_t)(n0 + (tid >> 2)) * K + (tid & 3) * 8;
  char* al = (char*)Alds + tid * 16;
  char* bl = (char*)Blds + tid * 16;

  for (int k0 = 0; k0 < K; k0 += 32) {
    __syncthreads();
    gl_lds16(ag + k0, al);
    gl_lds16(ag + (size_t)64 * K + k0, al + 4096);
    gl_lds16(bg + k0, bl);
    gl_lds16(bg + (size_t)64 * K + k0, bl + 4096);
    __syncthreads();
    short8 af[4], bfr[4];
#pragma unroll
    for (int mi = 0; mi < 4; ++mi)
      af[mi] = *(const short8*)((const char*)Alds +
                ((wr * 64 + mi * 16 + lr) * 64 + ls * 16));
#pragma unroll
    for (int ni = 0; ni < 4; ++ni)
      bfr[ni] = *(const short8*)((const char*)Blds +
                ((wc * 64 + ni * 16 + lr) * 64 + ls * 16));
#pragma unroll
    for (int mi = 0; mi < 4; ++mi)
#pragma unroll
      for (int ni = 0; ni < 4; ++ni)
        acc[mi][ni] = mfma_bf16(af[mi], bfr[ni], acc[mi][ni]);
  }

#pragma unroll
  for (int mi = 0; mi < 4; ++mi) {
#pragma unroll
    for (int ni = 0; ni < 4; ++ni) {
      int gr0 = m0 + wr * 64 + mi * 16 + (ls << 2);
      int gc = n0 + wc * 64 + ni * 16 + lr;
      float bv = bias[gc];
#pragma unroll
      for (int r = 0; r < 4; ++r) {
        int gr = gr0 + r;
        float v = acc[mi][ni][r] + bv;
        if (MODE == 3) {
          of32[(size_t)gr * D_ + gc] = v;
        } else {
          int b = gr >> 11, t = gr & (T_ - 1), h = gc >> 7, hd = gc & (HD_ - 1);
          size_t idx = (((size_t)(b * H_ + h) * T_) + t) * HD_ + hd;
          obf[idx] = f2bf(v);
          if (MODE == 1) of32[idx] = v;
        }
      }
    }
  }
}

// ---------------- causal flash attention ----------------
// grid: (T/64, B*H), block 256 = 4 independent waves, wave owns 16 q-rows.
__global__ __launch_bounds__(256) void attn_fwd(
    const short* __restrict__ qb, const short* __restrict__ kb,
    const short* __restrict__ vtb, short* __restrict__ aob) {
  __shared__ __attribute__((aligned(16))) short plds[4][16 * 32];
  int bh = blockIdx.y, qt = blockIdx.x;
  int tid = threadIdx.x, w = tid >> 6, lane = tid & 63;
  int q0 = qt * 64 + w * 16;
  int lr = lane & 15, ls = lane >> 4;
  const short* Q = qb + (size_t)bh * T_ * HD_;
  const short* Kp = kb + (size_t)bh * T_ * HD_;
  const short* Vt = vtb + (size_t)bh * HD_ * T_;

  short8 qf[4];
#pragma unroll
  for (int kk = 0; kk < 4; ++kk)
    qf[kk] = *(const short8*)&Q[(size_t)(q0 + lr) * HD_ + kk * 32 + ls * 8];

  f32x4 o[8] = {};
  float mrow[4] = {-1e30f, -1e30f, -1e30f, -1e30f};
  float lrow[4] = {0.f, 0.f, 0.f, 0.f};
  const float scale = 0.08838834764831845f;

  for (int kv0 = 0; kv0 < q0 + 16; kv0 += 32) {
    f32x4 s0 = {}, s1 = {};
#pragma unroll
    for (int kk = 0; kk < 4; ++kk) {
      short8 kf0 = *(const short8*)&Kp[(size_t)(kv0 + lr) * HD_ + kk * 32 + ls * 8];
      short8 kf1 = *(const short8*)&Kp[(size_t)(kv0 + 16 + lr) * HD_ + kk * 32 + ls * 8];
      s0 = mfma_bf16(qf[kk], kf0, s0);
      s1 = mfma_bf16(qf[kk], kf1, s1);
    }
    float al[4];
#pragma unroll
    for (int r = 0; r < 4; ++r) {
      int q = q0 + ls * 4 + r;
      float v0 = (kv0 + lr <= q) ? s0[r] * scale : -1e30f;
      float v1 = (kv0 + 16 + lr <= q) ? s1[r] * scale : -1e30f;
      float pm = fmaxf(v0, v1);
#pragma unroll
      for (int off = 1; off < 16; off <<= 1) pm = fmaxf(pm, __shfl_xor(pm, off));
      float mnew = fmaxf(mrow[r], pm);
      al[r] = __expf(mrow[r] - mnew);
      mrow[r] = mnew;
      float p0 = __expf(v0 - mnew);
      float p1 = __expf(v1 - mnew);
      float rs = p0 + p1;
#pragma unroll
      for (int off = 1; off < 16; off <<= 1) rs += __shfl_xor(rs, off);
      lrow[r] = lrow[r] * al[r] + rs;
      int row = ls * 4 + r;
      plds[w][row * 32 + lr] = f2bf(p0);
      plds[w][row * 32 + 16 + lr] = f2bf(p1);
    }
#pragma unroll
    for (int f = 0; f < 8; ++f)
#pragma unroll
      for (int r = 0; r < 4; ++r) o[f][r] *= al[r];

    short8 pf = *(const short8*)&plds[w][lr * 32 + ls * 8];
#pragma unroll
    for (int f = 0; f < 8; ++f) {
      short8 vf = *(const short8*)&Vt[(size_t)(f * 16 + lr) * T_ + kv0 + ls * 8];
      o[f] = mfma_bf16(pf, vf, o[f]);
    }
  }

  int b = bh >> 4, h = bh & 15;
#pragma unroll
  for (int r = 0; r < 4; ++r) {
    float inv = 1.0f / lrow[r];
    int q = q0 + ls * 4 + r;
    size_t rowoff = ((size_t)(b * T_ + q)) * D_ + h * HD_;
#pragma unroll
    for (int f = 0; f < 8; ++f)
      aob[rowoff + f * 16 + lr] = f2bf(o[f][r] * inv);
  }
}

extern "C" void kernel_launch(void* const* d_in, const int* in_sizes, int n_in,
                              void* d_out, int out_size, void* d_ws, size_t ws_size,
                              hipStream_t stream) {
  const float* x  = (const float*)d_in[0];
  const float* Wq = (const float*)d_in[1];
  const float* bq = (const float*)d_in[2];
  const float* Wk = (const float*)d_in[3];
  const float* bk = (const float*)d_in[4];
  const float* Wv = (const float*)d_in[5];
  const float* bv = (const float*)d_in[6];
  const float* Wo = (const float*)d_in[7];
  const float* bo = (const float*)d_in[8];
  float* out  = (float*)d_out;
  float* kout = out + (size_t)M_ * D_;
  float* vout = kout + (size_t)M_ * D_;

  char* ws = (char*)d_ws;
  auto alloc = [&](size_t bytes) {
    char* p = ws;
    ws += (bytes + 255) & ~(size_t)255;
    return p;
  };
  short* xb  = (short*)alloc((size_t)M_ * D_ * 2);
  short* wqT = (short*)alloc((size_t)D_ * D_ * 2);
  short* wkT = (short*)alloc((size_t)D_ * D_ * 2);
  short* wvT = (short*)alloc((size_t)D_ * D_ * 2);
  short* woT = (short*)alloc((size_t)D_ * D_ * 2);
  short* qb  = (short*)alloc((size_t)M_ * D_ * 2);
  short* kb  = (short*)alloc((size_t)M_ * D_ * 2);
  short* vb  = (short*)alloc((size_t)M_ * D_ * 2);
  short* vtb = wqT;  // reuse: wqT+wkT (16 MB contiguous) dead after Q/K GEMMs
  short* aob = xb;   // reuse: xb dead after V GEMM

  cast_f32_bf16<<<2048, 256, 0, stream>>>(x, xb, M_ * D_ / 4);
  dim3 tb(32, 8);
  transpose_cast_w<<<dim3(64, 64), tb, 0, stream>>>(Wq, wqT);
  transpose_cast_w<<<dim3(64, 64), tb, 0, stream>>>(Wk, wkT);
  transpose_cast_w<<<dim3(64, 64), tb, 0, stream>>>(Wv, wvT);
  transpose_cast_w<<<dim3(64, 64), tb, 0, stream>>>(Wo, woT);

  dim3 gg(D_ / 128, M_ / 128);
  gemm_bt<0><<<gg, 256, 0, stream>>>(xb, wqT, bq, qb, nullptr);
  gemm_bt<1><<<gg, 256, 0, stream>>>(xb, wkT, bk, kb, kout);
  gemm_bt<1><<<gg, 256, 0, stream>>>(xb, wvT, bv, vb, vout);
  transpose_v<<<dim3(T_ / 32, HD_ / 32, B_ * H_), tb, 0, stream>>>(vb, vtb);
  attn_fwd<<<dim3(T_ / 64, B_ * H_), 256, 0, stream>>>(qb, kb, vtb, aob);
  gemm_bt<3><<<gg, 256, 0, stream>>>(aob, woT, bo, nullptr, out);
}

// Round 2
// 475.982 us; speedup vs baseline: 1.5223x; 1.5223x over previous
//
#include <hip/hip_runtime.h>
#include <hip/hip_bf16.h>

#define B_ 2
#define T_ 2048
#define D_ 2048
#define H_ 16
#define HD_ 128
#define M_ 4096

typedef __attribute__((ext_vector_type(8))) short short8;
typedef __attribute__((ext_vector_type(8))) __bf16 bf16x8;
typedef __attribute__((ext_vector_type(4))) float f32x4;

__device__ __forceinline__ short f2bf(float f) {
  unsigned u = __builtin_bit_cast(unsigned, f);
  u += 0x7fffu + ((u >> 16) & 1u);
  return (short)(u >> 16);
}

__device__ __forceinline__ unsigned pk2(float lo, float hi) {
  return ((unsigned)(unsigned short)f2bf(hi) << 16) |
         (unsigned)(unsigned short)f2bf(lo);
}

__device__ __forceinline__ void gl_lds16(const void* g, void* l) {
  __builtin_amdgcn_global_load_lds(
      (const __attribute__((address_space(1))) unsigned int*)g,
      (__attribute__((address_space(3))) unsigned int*)l, 16, 0, 0);
}

__device__ __forceinline__ f32x4 mfma_bf16(short8 a, short8 b, f32x4 c) {
  return __builtin_amdgcn_mfma_f32_16x16x32_bf16(
      __builtin_bit_cast(bf16x8, a), __builtin_bit_cast(bf16x8, b), c, 0, 0, 0);
}

// ---------------- cast x -> bf16 ----------------
__global__ void cast_f32_bf16(const float* __restrict__ in, short* __restrict__ out, int n4) {
  int i = blockIdx.x * blockDim.x + threadIdx.x;
  int stride = gridDim.x * blockDim.x;
  for (; i < n4; i += stride) {
    float4 v = ((const float4*)in)[i];
    short4 s;
    s.x = f2bf(v.x); s.y = f2bf(v.y); s.z = f2bf(v.z); s.w = f2bf(v.w);
    ((short4*)out)[i] = s;
  }
}

// ---------------- W (K,N) f32 -> Wt (N,K) bf16 ----------------
__global__ void transpose_cast_w(const float* __restrict__ W, short* __restrict__ Wt) {
  __shared__ float t[32][33];
  int n0 = blockIdx.x * 32, k0 = blockIdx.y * 32;
  int tx = threadIdx.x, ty = threadIdx.y;
#pragma unroll
  for (int j = 0; j < 4; ++j)
    t[ty + j * 8][tx] = W[(size_t)(k0 + ty + j * 8) * D_ + n0 + tx];
  __syncthreads();
#pragma unroll
  for (int j = 0; j < 4; ++j)
    Wt[(size_t)(n0 + ty + j * 8) * D_ + k0 + tx] = f2bf(t[tx][ty + j * 8]);
}

// ---------------- v (bh,T,HD) bf16 -> vt (bh,HD,T) bf16 ----------------
__global__ void transpose_v(const short* __restrict__ vb, short* __restrict__ vtb) {
  __shared__ short t[32][33];
  int bh = blockIdx.z;
  int t0 = blockIdx.x * 32, h0 = blockIdx.y * 32;
  int tx = threadIdx.x, ty = threadIdx.y;
  const short* src = vb + (size_t)bh * T_ * HD_;
  short* dst = vtb + (size_t)bh * HD_ * T_;
#pragma unroll
  for (int j = 0; j < 4; ++j)
    t[ty + j * 8][tx] = src[(size_t)(t0 + ty + j * 8) * HD_ + h0 + tx];
  __syncthreads();
#pragma unroll
  for (int j = 0; j < 4; ++j)
    dst[(size_t)(h0 + ty + j * 8) * T_ + t0 + tx] = t[tx][ty + j * 8];
}

// ---------------- GEMM: C(M,N) = A(M,K)bf16 * Bt(N,K)bf16 + bias ----------------
template <int MODE>
__global__ __launch_bounds__(256) void gemm_bt(
    const short* __restrict__ A, const short* __restrict__ Bt,
    const float* __restrict__ bias, short* __restrict__ obf,
    float* __restrict__ of32) {
  __shared__ __attribute__((aligned(16))) short Alds[128 * 32];
  __shared__ __attribute__((aligned(16))) short Blds[128 * 32];
  const int K = D_;
  int tid = threadIdx.x;
  int m0 = blockIdx.y * 128, n0 = blockIdx.x * 128;
  int lane = tid & 63, w = tid >> 6, wr = w >> 1, wc = w & 1;
  int lr = lane & 15, ls = lane >> 4;
  f32x4 acc[4][4] = {};

  const short* ag = A + (size_t)(m0 + (tid >> 2)) * K + (tid & 3) * 8;
  const short* bg = Bt + (size_t)(n0 + (tid >> 2)) * K + (tid & 3) * 8;
  char* al = (char*)Alds + tid * 16;
  char* bl = (char*)Blds + tid * 16;

  for (int k0 = 0; k0 < K; k0 += 32) {
    __syncthreads();
    gl_lds16(ag + k0, al);
    gl_lds16(ag + (size_t)64 * K + k0, al + 4096);
    gl_lds16(bg + k0, bl);
    gl_lds16(bg + (size_t)64 * K + k0, bl + 4096);
    __syncthreads();
    short8 af[4], bfr[4];
#pragma unroll
    for (int mi = 0; mi < 4; ++mi)
      af[mi] = *(const short8*)((const char*)Alds +
                ((wr * 64 + mi * 16 + lr) * 64 + ls * 16));
#pragma unroll
    for (int ni = 0; ni < 4; ++ni)
      bfr[ni] = *(const short8*)((const char*)Blds +
                ((wc * 64 + ni * 16 + lr) * 64 + ls * 16));
#pragma unroll
    for (int mi = 0; mi < 4; ++mi)
#pragma unroll
      for (int ni = 0; ni < 4; ++ni)
        acc[mi][ni] = mfma_bf16(af[mi], bfr[ni], acc[mi][ni]);
  }

#pragma unroll
  for (int mi = 0; mi < 4; ++mi) {
#pragma unroll
    for (int ni = 0; ni < 4; ++ni) {
      int gr0 = m0 + wr * 64 + mi * 16 + (ls << 2);
      int gc = n0 + wc * 64 + ni * 16 + lr;
      float bv = bias[gc];
#pragma unroll
      for (int r = 0; r < 4; ++r) {
        int gr = gr0 + r;
        float v = acc[mi][ni][r] + bv;
        if (MODE == 3) {
          of32[(size_t)gr * D_ + gc] = v;
        } else {
          int b = gr >> 11, t = gr & (T_ - 1), h = gc >> 7, hd = gc & (HD_ - 1);
          size_t idx = (((size_t)(b * H_ + h) * T_) + t) * HD_ + hd;
          obf[idx] = f2bf(v);
          if (MODE == 1) of32[idx] = v;
        }
      }
    }
  }
}

// ---------------- causal flash attention (v2) ----------------
// grid (16, 32): 512 blocks; block handles q-tile pair {j, 31-j} -> uniform work.
// 4 independent waves/block, wave owns 16 q-rows. Swapped QK^T: lane owns one
// q-row (col = lane&15) -> softmax row-reduce is 2 shfl_xor steps.
__global__ __launch_bounds__(256) void attn_fwd(
    const short* __restrict__ qb, const short* __restrict__ kb,
    const short* __restrict__ vtb, short* __restrict__ aob) {
  __shared__ __attribute__((aligned(16))) short plds[4][16 * 40];  // pad 40 -> conflict-free
  __shared__ __attribute__((aligned(16))) float alds[4][16];

  // bijective XCD-chunked remap (512 = 8 * 64)
  int d = blockIdx.y * gridDim.x + blockIdx.x;
  int lg = (d & 7) * 64 + (d >> 3);
  int bh = lg >> 4;
  int jx = lg & 15;

  int tid = threadIdx.x, w = tid >> 6, lane = tid & 63;
  int lr = lane & 15, g = lane >> 4;
  const short* Q  = qb  + (size_t)bh * T_ * HD_;
  const short* Kp = kb  + (size_t)bh * T_ * HD_;
  const short* Vt = vtb + (size_t)bh * HD_ * T_;
  const float scale = 0.08838834764831845f;
  int b = bh >> 4, h = bh & 15;

  short* prow = &plds[w][0];
  float* arow = &alds[w][0];

#pragma unroll 1
  for (int pass = 0; pass < 2; ++pass) {
    int qt = pass ? (31 - jx) : jx;
    int q0 = qt * 64 + w * 16;
    int end = q0 + 16;

    short8 qf[4];
#pragma unroll
    for (int kk = 0; kk < 4; ++kk)
      qf[kk] = *(const short8*)&Q[(size_t)(q0 + lr) * HD_ + kk * 32 + g * 8];

    f32x4 o[8] = {};
    float mrow = -1e30f, lrow = 0.f;

    short8 kf[8];
#pragma unroll
    for (int kk = 0; kk < 4; ++kk) {
      kf[kk]     = *(const short8*)&Kp[(size_t)lr * HD_ + kk * 32 + g * 8];
      kf[4 + kk] = *(const short8*)&Kp[(size_t)(16 + lr) * HD_ + kk * 32 + g * 8];
    }

#pragma unroll 1
    for (int kv0 = 0; kv0 < end; kv0 += 32) {
      // V loads for this step (consumed after softmax -> latency hidden)
      short8 vf[8];
#pragma unroll
      for (int f = 0; f < 8; ++f)
        vf[f] = *(const short8*)&Vt[(size_t)(f * 16 + lr) * T_ + kv0 + g * 8];
      // K prefetch for next step (consumed next iteration)
      int kvp = (kv0 + 32 <= T_ - 32) ? kv0 + 32 : T_ - 32;
      short8 kn[8];
#pragma unroll
      for (int kk = 0; kk < 4; ++kk) {
        kn[kk]     = *(const short8*)&Kp[(size_t)(kvp + lr) * HD_ + kk * 32 + g * 8];
        kn[4 + kk] = *(const short8*)&Kp[(size_t)(kvp + 16 + lr) * HD_ + kk * 32 + g * 8];
      }

      // S = K . Q^T : col = q-local (lr), row = k-local (4g+r)
      f32x4 s0 = {}, s1 = {};
#pragma unroll
      for (int kk = 0; kk < 4; ++kk) {
        s0 = mfma_bf16(kf[kk], qf[kk], s0);
        s1 = mfma_bf16(kf[4 + kk], qf[kk], s1);
      }

      float vv[8];
#pragma unroll
      for (int r = 0; r < 4; ++r) {
        vv[r] = s0[r] * scale;
        vv[4 + r] = s1[r] * scale;
      }
      if (kv0 + 31 > q0) {  // wave-uniform branch; only tail steps masked
        int qrow = q0 + lr;
#pragma unroll
        for (int r = 0; r < 4; ++r) {
          if (kv0 + 4 * g + r > qrow) vv[r] = -1e30f;
          if (kv0 + 16 + 4 * g + r > qrow) vv[4 + r] = -1e30f;
        }
      }

      float pm = vv[0];
#pragma unroll
      for (int i = 1; i < 8; ++i) pm = fmaxf(pm, vv[i]);
      pm = fmaxf(pm, __shfl_xor(pm, 16));
      pm = fmaxf(pm, __shfl_xor(pm, 32));
      float mnew = fmaxf(mrow, pm);
      float al = __expf(mrow - mnew);
      mrow = mnew;

      float p[8];
      float rs = 0.f;
#pragma unroll
      for (int i = 0; i < 8; ++i) { p[i] = __expf(vv[i] - mnew); rs += p[i]; }
      rs += __shfl_xor(rs, 16);
      rs += __shfl_xor(rs, 32);
      lrow = lrow * al + rs;

      // pack P (row = q-local = lr, cols 4g..4g+3 and 16+4g..)
      uint2 w0, w1;
      w0.x = pk2(p[0], p[1]); w0.y = pk2(p[2], p[3]);
      w1.x = pk2(p[4], p[5]); w1.y = pk2(p[6], p[7]);
      *(uint2*)(prow + lr * 40 + 4 * g) = w0;
      *(uint2*)(prow + lr * 40 + 16 + 4 * g) = w1;
      if (!g) arow[lr] = al;

      // broadcast al into C-layout domain (q = 4g+r)
      f32x4 al4 = *(const f32x4*)(arow + 4 * g);
      // P fragment for PV: row = lr, k = 8g..8g+7
      short8 pf = *(const short8*)(prow + lr * 40 + 8 * g);
#pragma unroll
      for (int f = 0; f < 8; ++f) {
        o[f] *= al4;
        o[f] = mfma_bf16(pf, vf[f], o[f]);
      }
#pragma unroll
      for (int i = 0; i < 8; ++i) kf[i] = kn[i];
    }

    if (!g) arow[lr] = 1.0f / lrow;
    f32x4 l4 = *(const f32x4*)(arow + 4 * g);
#pragma unroll
    for (int r = 0; r < 4; ++r) {
      int q = q0 + 4 * g + r;
      size_t rowoff = ((size_t)(b * T_ + q)) * D_ + h * HD_;
#pragma unroll
      for (int f = 0; f < 8; ++f)
        aob[rowoff + f * 16 + lr] = f2bf(o[f][r] * l4[r]);
    }
  }
}

extern "C" void kernel_launch(void* const* d_in, const int* in_sizes, int n_in,
                              void* d_out, int out_size, void* d_ws, size_t ws_size,
                              hipStream_t stream) {
  const float* x  = (const float*)d_in[0];
  const float* Wq = (const float*)d_in[1];
  const float* bq = (const float*)d_in[2];
  const float* Wk = (const float*)d_in[3];
  const float* bk = (const float*)d_in[4];
  const float* Wv = (const float*)d_in[5];
  const float* bv = (const float*)d_in[6];
  const float* Wo = (const float*)d_in[7];
  const float* bo = (const float*)d_in[8];
  float* out  = (float*)d_out;
  float* kout = out + (size_t)M_ * D_;
  float* vout = kout + (size_t)M_ * D_;

  char* ws = (char*)d_ws;
  auto alloc = [&](size_t bytes) {
    char* p = ws;
    ws += (bytes + 255) & ~(size_t)255;
    return p;
  };
  short* xb  = (short*)alloc((size_t)M_ * D_ * 2);
  short* wqT = (short*)alloc((size_t)D_ * D_ * 2);
  short* wkT = (short*)alloc((size_t)D_ * D_ * 2);
  short* wvT = (short*)alloc((size_t)D_ * D_ * 2);
  short* woT = (short*)alloc((size_t)D_ * D_ * 2);
  short* qb  = (short*)alloc((size_t)M_ * D_ * 2);
  short* kb  = (short*)alloc((size_t)M_ * D_ * 2);
  short* vb  = (short*)alloc((size_t)M_ * D_ * 2);
  short* vtb = wqT;  // reuse: wqT+wkT (16 MB contiguous) dead after Q/K GEMMs
  short* aob = xb;   // reuse: xb dead after V GEMM

  cast_f32_bf16<<<2048, 256, 0, stream>>>(x, xb, M_ * D_ / 4);
  dim3 tb(32, 8);
  transpose_cast_w<<<dim3(64, 64), tb, 0, stream>>>(Wq, wqT);
  transpose_cast_w<<<dim3(64, 64), tb, 0, stream>>>(Wk, wkT);
  transpose_cast_w<<<dim3(64, 64), tb, 0, stream>>>(Wv, wvT);
  transpose_cast_w<<<dim3(64, 64), tb, 0, stream>>>(Wo, woT);

  dim3 gg(D_ / 128, M_ / 128);
  gemm_bt<0><<<gg, 256, 0, stream>>>(xb, wqT, bq, qb, nullptr);
  gemm_bt<1><<<gg, 256, 0, stream>>>(xb, wkT, bk, kb, kout);
  gemm_bt<1><<<gg, 256, 0, stream>>>(xb, wvT, bv, vb, vout);
  transpose_v<<<dim3(T_ / 32, HD_ / 32, B_ * H_), tb, 0, stream>>>(vb, vtb);
  attn_fwd<<<dim3(16, 32), 256, 0, stream>>>(qb, kb, vtb, aob);
  gemm_bt<3><<<gg, 256, 0, stream>>>(aob, woT, bo, nullptr, out);
}

// Round 3
// 473.213 us; speedup vs baseline: 1.5312x; 1.0059x over previous
//
#include <hip/hip_runtime.h>
#include <hip/hip_bf16.h>

#define B_ 2
#define T_ 2048
#define D_ 2048
#define H_ 16
#define HD_ 128
#define M_ 4096

typedef __attribute__((ext_vector_type(8))) short short8;
typedef __attribute__((ext_vector_type(8))) __bf16 bf16x8;
typedef __attribute__((ext_vector_type(4))) float f32x4;

__device__ __forceinline__ short f2bf(float f) {
  unsigned u = __builtin_bit_cast(unsigned, f);
  u += 0x7fffu + ((u >> 16) & 1u);
  return (short)(u >> 16);
}

__device__ __forceinline__ unsigned pk2(float lo, float hi) {
  return ((unsigned)(unsigned short)f2bf(hi) << 16) |
         (unsigned)(unsigned short)f2bf(lo);
}

__device__ __forceinline__ void gl_lds16(const void* g, void* l) {
  __builtin_amdgcn_global_load_lds(
      (const __attribute__((address_space(1))) unsigned int*)g,
      (__attribute__((address_space(3))) unsigned int*)l, 16, 0, 0);
}

__device__ __forceinline__ f32x4 mfma_bf16(short8 a, short8 b, f32x4 c) {
  return __builtin_amdgcn_mfma_f32_16x16x32_bf16(
      __builtin_bit_cast(bf16x8, a), __builtin_bit_cast(bf16x8, b), c, 0, 0, 0);
}

// ---------------- cast x -> bf16 ----------------
__global__ void cast_f32_bf16(const float* __restrict__ in, short* __restrict__ out, int n4) {
  int i = blockIdx.x * blockDim.x + threadIdx.x;
  int stride = gridDim.x * blockDim.x;
  for (; i < n4; i += stride) {
    float4 v = ((const float4*)in)[i];
    short4 s;
    s.x = f2bf(v.x); s.y = f2bf(v.y); s.z = f2bf(v.z); s.w = f2bf(v.w);
    ((short4*)out)[i] = s;
  }
}

// ---------------- W (K,N) f32 -> Wt (N,K) bf16 ----------------
__global__ void transpose_cast_w(const float* __restrict__ W, short* __restrict__ Wt) {
  __shared__ float t[32][33];
  int n0 = blockIdx.x * 32, k0 = blockIdx.y * 32;
  int tx = threadIdx.x, ty = threadIdx.y;
#pragma unroll
  for (int j = 0; j < 4; ++j)
    t[ty + j * 8][tx] = W[(size_t)(k0 + ty + j * 8) * D_ + n0 + tx];
  __syncthreads();
#pragma unroll
  for (int j = 0; j < 4; ++j)
    Wt[(size_t)(n0 + ty + j * 8) * D_ + k0 + tx] = f2bf(t[tx][ty + j * 8]);
}

// ---------------- v (bh,T,HD) bf16 -> vt (bh,HD,T) bf16 ----------------
__global__ void transpose_v(const short* __restrict__ vb, short* __restrict__ vtb) {
  __shared__ short t[32][33];
  int bh = blockIdx.z;
  int t0 = blockIdx.x * 32, h0 = blockIdx.y * 32;
  int tx = threadIdx.x, ty = threadIdx.y;
  const short* src = vb + (size_t)bh * T_ * HD_;
  short* dst = vtb + (size_t)bh * HD_ * T_;
#pragma unroll
  for (int j = 0; j < 4; ++j)
    t[ty + j * 8][tx] = src[(size_t)(t0 + ty + j * 8) * HD_ + h0 + tx];
  __syncthreads();
#pragma unroll
  for (int j = 0; j < 4; ++j)
    dst[(size_t)(h0 + ty + j * 8) * T_ + t0 + tx] = t[tx][ty + j * 8];
}

// ---------------- GEMM: C(M,N) = A(M,K)bf16 * Bt(N,K)bf16 + bias ----------------
template <int MODE>
__global__ __launch_bounds__(256) void gemm_bt(
    const short* __restrict__ A, const short* __restrict__ Bt,
    const float* __restrict__ bias, short* __restrict__ obf,
    float* __restrict__ of32) {
  __shared__ __attribute__((aligned(16))) short Alds[128 * 32];
  __shared__ __attribute__((aligned(16))) short Blds[128 * 32];
  const int K = D_;
  int tid = threadIdx.x;
  int m0 = blockIdx.y * 128, n0 = blockIdx.x * 128;
  int lane = tid & 63, w = tid >> 6, wr = w >> 1, wc = w & 1;
  int lr = lane & 15, ls = lane >> 4;
  f32x4 acc[4][4] = {};

  const short* ag = A + (size_t)(m0 + (tid >> 2)) * K + (tid & 3) * 8;
  const short* bg = Bt + (size_t)(n0 + (tid >> 2)) * K + (tid & 3) * 8;
  char* al = (char*)Alds + tid * 16;
  char* bl = (char*)Blds + tid * 16;

  for (int k0 = 0; k0 < K; k0 += 32) {
    __syncthreads();
    gl_lds16(ag + k0, al);
    gl_lds16(ag + (size_t)64 * K + k0, al + 4096);
    gl_lds16(bg + k0, bl);
    gl_lds16(bg + (size_t)64 * K + k0, bl + 4096);
    __syncthreads();
    short8 af[4], bfr[4];
#pragma unroll
    for (int mi = 0; mi < 4; ++mi)
      af[mi] = *(const short8*)((const char*)Alds +
                ((wr * 64 + mi * 16 + lr) * 64 + ls * 16));
#pragma unroll
    for (int ni = 0; ni < 4; ++ni)
      bfr[ni] = *(const short8*)((const char*)Blds +
                ((wc * 64 + ni * 16 + lr) * 64 + ls * 16));
#pragma unroll
    for (int mi = 0; mi < 4; ++mi)
#pragma unroll
      for (int ni = 0; ni < 4; ++ni)
        acc[mi][ni] = mfma_bf16(af[mi], bfr[ni], acc[mi][ni]);
  }

#pragma unroll
  for (int mi = 0; mi < 4; ++mi) {
#pragma unroll
    for (int ni = 0; ni < 4; ++ni) {
      int gr0 = m0 + wr * 64 + mi * 16 + (ls << 2);
      int gc = n0 + wc * 64 + ni * 16 + lr;
      float bv = bias[gc];
#pragma unroll
      for (int r = 0; r < 4; ++r) {
        int gr = gr0 + r;
        float v = acc[mi][ni][r] + bv;
        if (MODE == 3) {
          of32[(size_t)gr * D_ + gc] = v;
        } else {
          int b = gr >> 11, t = gr & (T_ - 1), h = gc >> 7, hd = gc & (HD_ - 1);
          size_t idx = (((size_t)(b * H_ + h) * T_) + t) * HD_ + hd;
          obf[idx] = f2bf(v);
          if (MODE == 1) of32[idx] = v;
        }
      }
    }
  }
}

// ---------------- causal flash attention (v3) ----------------
// grid (16, 32): block = q-tile pair {j, 31-j}; 4 waves, wave = 16 q-rows.
// Swapped QK^T (lane owns one q-row). Ping-pong K prefetch (no reg copies),
// V loaded at step top / used after softmax, defer-max rescale (THR=8).
__global__ __launch_bounds__(256) void attn_fwd(
    const short* __restrict__ qb, const short* __restrict__ kb,
    const short* __restrict__ vtb, short* __restrict__ aob) {
  __shared__ __attribute__((aligned(16))) short plds[4][16 * 40];
  __shared__ __attribute__((aligned(16))) float alds[4][16];

  int d = blockIdx.y * gridDim.x + blockIdx.x;
  int lg = (d & 7) * 64 + (d >> 3);
  int bh = lg >> 4;
  int jx = lg & 15;

  int tid = threadIdx.x, w = tid >> 6, lane = tid & 63;
  int lr = lane & 15, g = lane >> 4;
  const short* Q  = qb  + (size_t)bh * T_ * HD_;
  const short* Kp = kb  + (size_t)bh * T_ * HD_;
  const short* Vt = vtb + (size_t)bh * HD_ * T_;
  const float scale = 0.08838834764831845f;
  int b = bh >> 4, h = bh & 15;

  short* prow = &plds[w][0];
  float* arow = &alds[w][0];

#pragma unroll 1
  for (int pass = 0; pass < 2; ++pass) {
    int qt = pass ? (31 - jx) : jx;
    int q0 = qt * 64 + w * 16;
    int end = q0 + 16;
    int nsteps = (end + 31) >> 5;

    short8 qf[4];
#pragma unroll
    for (int kk = 0; kk < 4; ++kk)
      qf[kk] = *(const short8*)&Q[(size_t)(q0 + lr) * HD_ + kk * 32 + g * 8];

    f32x4 o[8] = {};
    float mrow = -1e30f, lrow = 0.f;

    short8 K0[8], K1[8];
#pragma unroll
    for (int kk = 0; kk < 4; ++kk) {
      K0[kk]     = *(const short8*)&Kp[(size_t)lr * HD_ + kk * 32 + g * 8];
      K0[4 + kk] = *(const short8*)&Kp[(size_t)(16 + lr) * HD_ + kk * 32 + g * 8];
    }

    auto STEP = [&](int kv, short8 (&KF)[8], short8 (&KN)[8], int kvp, bool dopf) {
      // V for this step: issued first, consumed after QK^T+softmax
      short8 vf[8];
#pragma unroll
      for (int f = 0; f < 8; ++f)
        vf[f] = *(const short8*)&Vt[(size_t)(f * 16 + lr) * T_ + kv + g * 8];
      if (dopf) {
#pragma unroll
        for (int kk = 0; kk < 4; ++kk) {
          KN[kk]     = *(const short8*)&Kp[(size_t)(kvp + lr) * HD_ + kk * 32 + g * 8];
          KN[4 + kk] = *(const short8*)&Kp[(size_t)(kvp + 16 + lr) * HD_ + kk * 32 + g * 8];
        }
      }

      f32x4 s0 = {}, s1 = {};
      __builtin_amdgcn_s_setprio(1);
#pragma unroll
      for (int kk = 0; kk < 4; ++kk) {
        s0 = mfma_bf16(KF[kk], qf[kk], s0);
        s1 = mfma_bf16(KF[4 + kk], qf[kk], s1);
      }
      __builtin_amdgcn_s_setprio(0);

      float vv[8];
#pragma unroll
      for (int r = 0; r < 4; ++r) {
        vv[r] = s0[r] * scale;
        vv[4 + r] = s1[r] * scale;
      }
      if (kv + 31 > q0) {
        int qrow = q0 + lr;
#pragma unroll
        for (int r = 0; r < 4; ++r) {
          if (kv + 4 * g + r > qrow) vv[r] = -1e30f;
          if (kv + 16 + 4 * g + r > qrow) vv[4 + r] = -1e30f;
        }
      }

      float pm = vv[0];
#pragma unroll
      for (int i = 1; i < 8; ++i) pm = fmaxf(pm, vv[i]);
      pm = fmaxf(pm, __shfl_xor(pm, 16));
      pm = fmaxf(pm, __shfl_xor(pm, 32));

      bool rescale = !__all(pm - mrow <= 8.0f);
      float al = 1.0f;
      if (rescale) {
        float mnew = fmaxf(mrow, pm);
        al = __expf(mrow - mnew);
        mrow = mnew;
      }

      float p[8];
      float rs = 0.f;
#pragma unroll
      for (int i = 0; i < 8; ++i) { p[i] = __expf(vv[i] - mrow); rs += p[i]; }
      rs += __shfl_xor(rs, 16);
      rs += __shfl_xor(rs, 32);
      lrow = (rescale ? lrow * al : lrow) + rs;

      uint2 w0, w1;
      w0.x = pk2(p[0], p[1]); w0.y = pk2(p[2], p[3]);
      w1.x = pk2(p[4], p[5]); w1.y = pk2(p[6], p[7]);
      *(uint2*)(prow + lr * 40 + 4 * g) = w0;
      *(uint2*)(prow + lr * 40 + 16 + 4 * g) = w1;

      if (rescale) {
        if (!g) arow[lr] = al;
        f32x4 al4 = *(const f32x4*)(arow + 4 * g);
#pragma unroll
        for (int f = 0; f < 8; ++f) o[f] *= al4;
      }

      short8 pfr = *(const short8*)(prow + lr * 40 + 8 * g);
      __builtin_amdgcn_s_setprio(1);
#pragma unroll
      for (int f = 0; f < 8; ++f) o[f] = mfma_bf16(pfr, vf[f], o[f]);
      __builtin_amdgcn_s_setprio(0);
    };

    int kv0 = 0;
#pragma unroll 1
    for (int s = 0; s + 2 <= nsteps; s += 2) {
      STEP(kv0, K0, K1, kv0 + 32, true);
      STEP(kv0 + 32, K1, K0, kv0 + 64, (s + 2) < nsteps);
      kv0 += 64;
    }
    if (nsteps & 1) STEP(kv0, K0, K1, 0, false);

    if (!g) arow[lr] = 1.0f / lrow;
    f32x4 l4 = *(const f32x4*)(arow + 4 * g);
#pragma unroll
    for (int r = 0; r < 4; ++r) {
      int q = q0 + 4 * g + r;
      size_t rowoff = ((size_t)(b * T_ + q)) * D_ + h * HD_;
#pragma unroll
      for (int f = 0; f < 8; ++f)
        aob[rowoff + f * 16 + lr] = f2bf(o[f][r] * l4[r]);
    }
  }
}

extern "C" void kernel_launch(void* const* d_in, const int* in_sizes, int n_in,
                              void* d_out, int out_size, void* d_ws, size_t ws_size,
                              hipStream_t stream) {
  const float* x  = (const float*)d_in[0];
  const float* Wq = (const float*)d_in[1];
  const float* bq = (const float*)d_in[2];
  const float* Wk = (const float*)d_in[3];
  const float* bk = (const float*)d_in[4];
  const float* Wv = (const float*)d_in[5];
  const float* bv = (const float*)d_in[6];
  const float* Wo = (const float*)d_in[7];
  const float* bo = (const float*)d_in[8];
  float* out  = (float*)d_out;
  float* kout = out + (size_t)M_ * D_;
  float* vout = kout + (size_t)M_ * D_;

  char* ws = (char*)d_ws;
  auto alloc = [&](size_t bytes) {
    char* p = ws;
    ws += (bytes + 255) & ~(size_t)255;
    return p;
  };
  short* xb  = (short*)alloc((size_t)M_ * D_ * 2);
  short* wqT = (short*)alloc((size_t)D_ * D_ * 2);
  short* wkT = (short*)alloc((size_t)D_ * D_ * 2);
  short* wvT = (short*)alloc((size_t)D_ * D_ * 2);
  short* woT = (short*)alloc((size_t)D_ * D_ * 2);
  short* qb  = (short*)alloc((size_t)M_ * D_ * 2);
  short* kb  = (short*)alloc((size_t)M_ * D_ * 2);
  short* vb  = (short*)alloc((size_t)M_ * D_ * 2);
  short* vtb = wqT;  // reuse: wqT+wkT (16 MB contiguous) dead after Q/K GEMMs
  short* aob = xb;   // reuse: xb dead after V GEMM

  cast_f32_bf16<<<2048, 256, 0, stream>>>(x, xb, M_ * D_ / 4);
  dim3 tb(32, 8);
  transpose_cast_w<<<dim3(64, 64), tb, 0, stream>>>(Wq, wqT);
  transpose_cast_w<<<dim3(64, 64), tb, 0, stream>>>(Wk, wkT);
  transpose_cast_w<<<dim3(64, 64), tb, 0, stream>>>(Wv, wvT);
  transpose_cast_w<<<dim3(64, 64), tb, 0, stream>>>(Wo, woT);

  dim3 gg(D_ / 128, M_ / 128);
  gemm_bt<0><<<gg, 256, 0, stream>>>(xb, wqT, bq, qb, nullptr);
  gemm_bt<1><<<gg, 256, 0, stream>>>(xb, wkT, bk, kb, kout);
  gemm_bt<1><<<gg, 256, 0, stream>>>(xb, wvT, bv, vb, vout);
  transpose_v<<<dim3(T_ / 32, HD_ / 32, B_ * H_), tb, 0, stream>>>(vb, vtb);
  attn_fwd<<<dim3(16, 32), 256, 0, stream>>>(qb, kb, vtb, aob);
  gemm_bt<3><<<gg, 256, 0, stream>>>(aob, woT, bo, nullptr, out);
}

// Round 4
// 315.324 us; speedup vs baseline: 2.2979x; 1.5007x over previous
//
#include <hip/hip_runtime.h>
#include <hip/hip_bf16.h>

#define B_ 2
#define T_ 2048
#define D_ 2048
#define H_ 16
#define HD_ 128
#define M_ 4096

typedef __attribute__((ext_vector_type(8))) short short8;
typedef __attribute__((ext_vector_type(8))) __bf16 bf16x8;
typedef __attribute__((ext_vector_type(4))) float f32x4;
typedef __attribute__((ext_vector_type(4))) unsigned uint32x4;

__device__ __forceinline__ short f2bf(float f) {
  unsigned u = __builtin_bit_cast(unsigned, f);
  u += 0x7fffu + ((u >> 16) & 1u);
  return (short)(u >> 16);
}

__device__ __forceinline__ unsigned pk2(float lo, float hi) {
  return ((unsigned)(unsigned short)f2bf(hi) << 16) |
         (unsigned)(unsigned short)f2bf(lo);
}

__device__ __forceinline__ void gl_lds16(const void* g, void* l) {
  __builtin_amdgcn_global_load_lds(
      (const __attribute__((address_space(1))) unsigned int*)g,
      (__attribute__((address_space(3))) unsigned int*)l, 16, 0, 0);
}

__device__ __forceinline__ f32x4 mfma_bf16(short8 a, short8 b, f32x4 c) {
  return __builtin_amdgcn_mfma_f32_16x16x32_bf16(
      __builtin_bit_cast(bf16x8, a), __builtin_bit_cast(bf16x8, b), c, 0, 0, 0);
}

// permlane swap helpers. sw*(x): returns {even-member value, odd-member value}
// of the lane-pair groups (16-swap: groups g/g^1; 32-swap: lane/lane^32).
// The v_mov forces a distinct register so vdst != vsrc.
__device__ __forceinline__ float2 sw16f(float x) {
  float a = x, bv;
  asm("v_mov_b32 %0, %1" : "=v"(bv) : "v"(x));
  asm("v_permlane16_swap_b32 %0, %1" : "+v"(a), "+v"(bv));
  return make_float2(a, bv);
}
__device__ __forceinline__ float2 sw32f(float x) {
  float a = x, bv;
  asm("v_mov_b32 %0, %1" : "=v"(bv) : "v"(x));
  asm("v_permlane32_swap_b32 %0, %1" : "+v"(a), "+v"(bv));
  return make_float2(a, bv);
}
__device__ __forceinline__ void sw16u(unsigned x, unsigned& e, unsigned& o) {
  unsigned a = x, bv;
  asm("v_mov_b32 %0, %1" : "=v"(bv) : "v"(x));
  asm("v_permlane16_swap_b32 %0, %1" : "+v"(a), "+v"(bv));
  e = a; o = bv;
}
__device__ __forceinline__ void pl32u(unsigned& a, unsigned& b) {
  asm("v_permlane32_swap_b32 %0, %1" : "+v"(a), "+v"(b));
}

// ---------------- cast x -> bf16 ----------------
__global__ void cast_f32_bf16(const float* __restrict__ in, short* __restrict__ out, int n4) {
  int i = blockIdx.x * blockDim.x + threadIdx.x;
  int stride = gridDim.x * blockDim.x;
  for (; i < n4; i += stride) {
    float4 v = ((const float4*)in)[i];
    short4 s;
    s.x = f2bf(v.x); s.y = f2bf(v.y); s.z = f2bf(v.z); s.w = f2bf(v.w);
    ((short4*)out)[i] = s;
  }
}

// ---------------- W (K,N) f32 -> Wt (N,K) bf16 ----------------
__global__ void transpose_cast_w(const float* __restrict__ W, short* __restrict__ Wt) {
  __shared__ float t[32][33];
  int n0 = blockIdx.x * 32, k0 = blockIdx.y * 32;
  int tx = threadIdx.x, ty = threadIdx.y;
#pragma unroll
  for (int j = 0; j < 4; ++j)
    t[ty + j * 8][tx] = W[(size_t)(k0 + ty + j * 8) * D_ + n0 + tx];
  __syncthreads();
#pragma unroll
  for (int j = 0; j < 4; ++j)
    Wt[(size_t)(n0 + ty + j * 8) * D_ + k0 + tx] = f2bf(t[tx][ty + j * 8]);
}

// ---------------- v (bh,T,HD) bf16 -> vt (bh,HD,T) bf16 ----------------
__global__ void transpose_v(const short* __restrict__ vb, short* __restrict__ vtb) {
  __shared__ short t[32][33];
  int bh = blockIdx.z;
  int t0 = blockIdx.x * 32, h0 = blockIdx.y * 32;
  int tx = threadIdx.x, ty = threadIdx.y;
  const short* src = vb + (size_t)bh * T_ * HD_;
  short* dst = vtb + (size_t)bh * HD_ * T_;
#pragma unroll
  for (int j = 0; j < 4; ++j)
    t[ty + j * 8][tx] = src[(size_t)(t0 + ty + j * 8) * HD_ + h0 + tx];
  __syncthreads();
#pragma unroll
  for (int j = 0; j < 4; ++j)
    dst[(size_t)(h0 + ty + j * 8) * T_ + t0 + tx] = t[tx][ty + j * 8];
}

// ---------------- GEMM: C(M,N) = A(M,K)bf16 * Bt(N,K)bf16 + bias ----------------
template <int MODE>
__global__ __launch_bounds__(256) void gemm_bt(
    const short* __restrict__ A, const short* __restrict__ Bt,
    const float* __restrict__ bias, short* __restrict__ obf,
    float* __restrict__ of32) {
  __shared__ __attribute__((aligned(16))) short Alds[128 * 32];
  __shared__ __attribute__((aligned(16))) short Blds[128 * 32];
  const int K = D_;
  int tid = threadIdx.x;
  int m0 = blockIdx.y * 128, n0 = blockIdx.x * 128;
  int lane = tid & 63, w = tid >> 6, wr = w >> 1, wc = w & 1;
  int lr = lane & 15, ls = lane >> 4;
  f32x4 acc[4][4] = {};

  const short* ag = A + (size_t)(m0 + (tid >> 2)) * K + (tid & 3) * 8;
  const short* bg = Bt + (size_t)(n0 + (tid >> 2)) * K + (tid & 3) * 8;
  char* al = (char*)Alds + tid * 16;
  char* bl = (char*)Blds + tid * 16;

  for (int k0 = 0; k0 < K; k0 += 32) {
    __syncthreads();
    gl_lds16(ag + k0, al);
    gl_lds16(ag + (size_t)64 * K + k0, al + 4096);
    gl_lds16(bg + k0, bl);
    gl_lds16(bg + (size_t)64 * K + k0, bl + 4096);
    __syncthreads();
    short8 af[4], bfr[4];
#pragma unroll
    for (int mi = 0; mi < 4; ++mi)
      af[mi] = *(const short8*)((const char*)Alds +
                ((wr * 64 + mi * 16 + lr) * 64 + ls * 16));
#pragma unroll
    for (int ni = 0; ni < 4; ++ni)
      bfr[ni] = *(const short8*)((const char*)Blds +
                ((wc * 64 + ni * 16 + lr) * 64 + ls * 16));
#pragma unroll
    for (int mi = 0; mi < 4; ++mi)
#pragma unroll
      for (int ni = 0; ni < 4; ++ni)
        acc[mi][ni] = mfma_bf16(af[mi], bfr[ni], acc[mi][ni]);
  }

#pragma unroll
  for (int mi = 0; mi < 4; ++mi) {
#pragma unroll
    for (int ni = 0; ni < 4; ++ni) {
      int gr0 = m0 + wr * 64 + mi * 16 + (ls << 2);
      int gc = n0 + wc * 64 + ni * 16 + lr;
      float bv = bias[gc];
#pragma unroll
      for (int r = 0; r < 4; ++r) {
        int gr = gr0 + r;
        float v = acc[mi][ni][r] + bv;
        if (MODE == 3) {
          of32[(size_t)gr * D_ + gc] = v;
        } else {
          int b = gr >> 11, t = gr & (T_ - 1), h = gc >> 7, hd = gc & (HD_ - 1);
          size_t idx = (((size_t)(b * H_ + h) * T_) + t) * HD_ + hd;
          obf[idx] = f2bf(v);
          if (MODE == 1) of32[idx] = v;
        }
      }
    }
  }
}

// ---------------- causal flash attention (v4) ----------------
// grid (16,32): block = q-tile pair {j,31-j}; 4 waves x 16 q-rows, KVBLK=32.
// K/V staged in LDS (shared by all 4 waves), double-buffered, 2-phase schedule.
// K staged with inverse-XOR-swizzled global source + XOR on ds_read (rule #21).
// Swapped QK^T; softmax reduce + P redistribution via permlane swaps (no LDS).
__global__ __launch_bounds__(256, 2) void attn_fwd(
    const short* __restrict__ qb, const short* __restrict__ kb,
    const short* __restrict__ vtb, short* __restrict__ aob) {
  __shared__ __attribute__((aligned(16))) char kvlds[2][16384];  // [buf]: K 8K | V 8K

  int d = blockIdx.y * gridDim.x + blockIdx.x;
  int lg = (d & 7) * 64 + (d >> 3);
  int bh = lg >> 4, jx = lg & 15;

  int tid = threadIdx.x, w = tid >> 6, lane = tid & 63;
  int lr = lane & 15, g = lane >> 4;
  const short* Q  = qb  + (size_t)bh * T_ * HD_;
  const short* Kp = kb  + (size_t)bh * T_ * HD_;
  const short* Vt = vtb + (size_t)bh * HD_ * T_;
  const float scale = 0.08838834764831845f;
  int b = bh >> 4, h = bh & 15;
  bool hi16 = (lane & 16) != 0;

  // staging invariants: wave w stages LDS bytes [w*2048, w*2048+2048) of each tile
  int oA = ((2 * w + 0) * 64 + lane) * 16;
  int oB = ((2 * w + 1) * 64 + lane) * 16;
  int rKA = oA >> 8, rKB = oB >> 8;                       // K row (256B rows)
  size_t skA = (size_t)rKA * HD_ + (((oA & 255) ^ ((rKA & 7) << 4)) >> 1);
  size_t skB = (size_t)rKB * HD_ + (((oB & 255) ^ ((rKB & 7) << 4)) >> 1);
  int rVA = oA >> 6, rVB = oB >> 6;                       // V row (64B rows)
  size_t svA = (size_t)rVA * T_ + (((oA & 63) ^ ((rVA & 3) << 4)) >> 1);
  size_t svB = (size_t)rVB * T_ + (((oB & 63) ^ ((rVB & 3) << 4)) >> 1);

#pragma unroll 1
  for (int pass = 0; pass < 2; ++pass) {
    int qt = pass ? (31 - jx) : jx;
    int q0 = qt * 64 + w * 16;
    int ntiles = 2 * qt + 2;

    // prologue: stage tile 0 into buf 0
    {
      char* kd = &kvlds[0][0];
      char* vd = &kvlds[0][8192];
      gl_lds16(Kp + skA, kd + oA);
      gl_lds16(Kp + skB, kd + oB);
      gl_lds16(Vt + svA, vd + oA);
      gl_lds16(Vt + svB, vd + oB);
    }

    short8 qf[4];
#pragma unroll
    for (int kk = 0; kk < 4; ++kk)
      qf[kk] = *(const short8*)&Q[(size_t)(q0 + lr) * HD_ + kk * 32 + g * 8];

    f32x4 o[8] = {};
    float mrow = -1e30f, lrow = 0.f;
    __syncthreads();

#pragma unroll 1
    for (int t = 0; t < ntiles; ++t) {
      int kv0 = t * 32, buf = t & 1;
      // stage next tile first (latency overlaps this tile's compute)
      if (t + 1 < ntiles) {
        char* kd = &kvlds[buf ^ 1][0];
        char* vd = &kvlds[buf ^ 1][8192];
        const short* Kn = Kp + (size_t)(kv0 + 32) * HD_;
        const short* Vn = Vt + (kv0 + 32);
        gl_lds16(Kn + skA, kd + oA);
        gl_lds16(Kn + skB, kd + oB);
        gl_lds16(Vn + svA, vd + oA);
        gl_lds16(Vn + svB, vd + oB);
      }
      if (kv0 < q0 + 16) {  // wave-uniform active check
        const char* kb_ = &kvlds[buf][0];
        const char* vb_ = &kvlds[buf][8192];
        short8 kf0[4], kf1[4], vf[8];
#pragma unroll
        for (int kk = 0; kk < 4; ++kk) {
          int cs = (kk * 64 + g * 16) ^ ((lr & 7) << 4);
          kf0[kk] = *(const short8*)(kb_ + (lr * 256 + cs));
          kf1[kk] = *(const short8*)(kb_ + ((16 + lr) * 256 + cs));
        }
#pragma unroll
        for (int f = 0; f < 8; ++f)
          vf[f] = *(const short8*)(vb_ + ((f * 16 + lr) * 64 +
                   ((g * 16) ^ ((lr & 3) << 4))));

        f32x4 s0 = {}, s1 = {};
        __builtin_amdgcn_s_setprio(1);
#pragma unroll
        for (int kk = 0; kk < 4; ++kk) {
          s0 = mfma_bf16(kf0[kk], qf[kk], s0);
          s1 = mfma_bf16(kf1[kk], qf[kk], s1);
        }
        __builtin_amdgcn_s_setprio(0);

        float vv[8];
#pragma unroll
        for (int r = 0; r < 4; ++r) {
          vv[r] = s0[r] * scale;
          vv[4 + r] = s1[r] * scale;
        }
        if (kv0 + 31 > q0) {
          int qrow = q0 + lr;
#pragma unroll
          for (int r = 0; r < 4; ++r) {
            if (kv0 + 4 * g + r > qrow) vv[r] = -1e30f;
            if (kv0 + 16 + 4 * g + r > qrow) vv[4 + r] = -1e30f;
          }
        }

        // row max (q-row = lr): combine 4 g-groups via permlane swaps (VALU)
        float pm = vv[0];
#pragma unroll
        for (int i = 1; i < 8; ++i) pm = fmaxf(pm, vv[i]);
        { float2 tpm = sw32f(pm); pm = fmaxf(tpm.x, tpm.y); }
        { float2 tpm = sw16f(pm); pm = fmaxf(tpm.x, tpm.y); }

        bool rescale = !__all(pm - mrow <= 8.0f);
        float alpha = 1.0f;
        if (rescale) {
          float mnew = fmaxf(mrow, pm);
          alpha = __expf(mrow - mnew);
          mrow = mnew;
        }

        float p[8];
        float rs = 0.f;
#pragma unroll
        for (int i = 0; i < 8; ++i) { p[i] = __expf(vv[i] - mrow); rs += p[i]; }
        { float2 trs = sw32f(rs); rs = trs.x + trs.y; }
        { float2 trs = sw16f(rs); rs = trs.x + trs.y; }
        lrow = (rescale ? lrow * alpha : lrow) + rs;

        if (rescale) {
          float alr[4];
#pragma unroll
          for (int r = 0; r < 4; ++r) alr[r] = __shfl(alpha, 4 * g + r);
#pragma unroll
          for (int f = 0; f < 8; ++f)
#pragma unroll
            for (int r = 0; r < 4; ++r) o[f][r] *= alr[r];
        }

        // P (lane owns q=lr, k = 4g..4g+3 & 16+4g..) -> A-frag (k = 8g..8g+7)
        unsigned w0 = pk2(p[0], p[1]), w1 = pk2(p[2], p[3]);
        unsigned w2 = pk2(p[4], p[5]), w3 = pk2(p[6], p[7]);
        unsigned e0, od0, e1, od1, e2, od2, e3, od3;
        sw16u(w0, e0, od0); sw16u(w1, e1, od1);
        sw16u(w2, e2, od2); sw16u(w3, e3, od3);
        // FT = {e0,e1,od0,od1} (k: first 16), ST = {e2,e3,od2,od3} (k: 16..31)
        unsigned F0 = e0,  S0 = e2;  pl32u(F0, S0);
        unsigned F1 = e1,  S1 = e3;  pl32u(F1, S1);
        unsigned F2 = od0, S2 = od2; pl32u(F2, S2);
        unsigned F3 = od1, S3 = od3; pl32u(F3, S3);
        uint32x4 paw = { hi16 ? S0 : F0, hi16 ? S1 : F1,
                         hi16 ? S2 : F2, hi16 ? S3 : F3 };
        short8 pa = __builtin_bit_cast(short8, paw);

        __builtin_amdgcn_s_setprio(1);
#pragma unroll
        for (int f = 0; f < 8; ++f) o[f] = mfma_bf16(pa, vf[f], o[f]);
        __builtin_amdgcn_s_setprio(0);
      }
      __syncthreads();  // drains staging vmcnt; next tile ready
    }

    float inv = 1.0f / lrow;
    float invr[4];
#pragma unroll
    for (int r = 0; r < 4; ++r) invr[r] = __shfl(inv, 4 * g + r);
#pragma unroll
    for (int r = 0; r < 4; ++r) {
      int q = q0 + 4 * g + r;
      size_t rowoff = ((size_t)(b * T_ + q)) * D_ + h * HD_;
#pragma unroll
      for (int f = 0; f < 8; ++f)
        aob[rowoff + f * 16 + lr] = f2bf(o[f][r] * invr[r]);
    }
  }
}

extern "C" void kernel_launch(void* const* d_in, const int* in_sizes, int n_in,
                              void* d_out, int out_size, void* d_ws, size_t ws_size,
                              hipStream_t stream) {
  const float* x  = (const float*)d_in[0];
  const float* Wq = (const float*)d_in[1];
  const float* bq = (const float*)d_in[2];
  const float* Wk = (const float*)d_in[3];
  const float* bk = (const float*)d_in[4];
  const float* Wv = (const float*)d_in[5];
  const float* bv = (const float*)d_in[6];
  const float* Wo = (const float*)d_in[7];
  const float* bo = (const float*)d_in[8];
  float* out  = (float*)d_out;
  float* kout = out + (size_t)M_ * D_;
  float* vout = kout + (size_t)M_ * D_;

  char* ws = (char*)d_ws;
  auto alloc = [&](size_t bytes) {
    char* p = ws;
    ws += (bytes + 255) & ~(size_t)255;
    return p;
  };
  short* xb  = (short*)alloc((size_t)M_ * D_ * 2);
  short* wqT = (short*)alloc((size_t)D_ * D_ * 2);
  short* wkT = (short*)alloc((size_t)D_ * D_ * 2);
  short* wvT = (short*)alloc((size_t)D_ * D_ * 2);
  short* woT = (short*)alloc((size_t)D_ * D_ * 2);
  short* qb  = (short*)alloc((size_t)M_ * D_ * 2);
  short* kb  = (short*)alloc((size_t)M_ * D_ * 2);
  short* vb  = (short*)alloc((size_t)M_ * D_ * 2);
  short* vtb = wqT;  // reuse: wqT+wkT (16 MB contiguous) dead after Q/K GEMMs
  short* aob = xb;   // reuse: xb dead after V GEMM

  cast_f32_bf16<<<2048, 256, 0, stream>>>(x, xb, M_ * D_ / 4);
  dim3 tb(32, 8);
  transpose_cast_w<<<dim3(64, 64), tb, 0, stream>>>(Wq, wqT);
  transpose_cast_w<<<dim3(64, 64), tb, 0, stream>>>(Wk, wkT);
  transpose_cast_w<<<dim3(64, 64), tb, 0, stream>>>(Wv, wvT);
  transpose_cast_w<<<dim3(64, 64), tb, 0, stream>>>(Wo, woT);

  dim3 gg(D_ / 128, M_ / 128);
  gemm_bt<0><<<gg, 256, 0, stream>>>(xb, wqT, bq, qb, nullptr);
  gemm_bt<1><<<gg, 256, 0, stream>>>(xb, wkT, bk, kb, kout);
  gemm_bt<1><<<gg, 256, 0, stream>>>(xb, wvT, bv, vb, vout);
  transpose_v<<<dim3(T_ / 32, HD_ / 32, B_ * H_), tb, 0, stream>>>(vb, vtb);
  attn_fwd<<<dim3(16, 32), 256, 0, stream>>>(qb, kb, vtb, aob);
  gemm_bt<3><<<gg, 256, 0, stream>>>(aob, woT, bo, nullptr, out);
}

// Round 5
// 293.433 us; speedup vs baseline: 2.4693x; 1.0746x over previous
//
#include <hip/hip_runtime.h>
#include <hip/hip_bf16.h>

#define B_ 2
#define T_ 2048
#define D_ 2048
#define H_ 16
#define HD_ 128
#define M_ 4096

typedef __attribute__((ext_vector_type(8))) short short8;
typedef __attribute__((ext_vector_type(8))) __bf16 bf16x8;
typedef __attribute__((ext_vector_type(4))) float f32x4;
typedef __attribute__((ext_vector_type(4))) unsigned uint32x4;

__device__ __forceinline__ short f2bf(float f) {
  unsigned u = __builtin_bit_cast(unsigned, f);
  u += 0x7fffu + ((u >> 16) & 1u);
  return (short)(u >> 16);
}

__device__ __forceinline__ unsigned pk2(float lo, float hi) {
  return ((unsigned)(unsigned short)f2bf(hi) << 16) |
         (unsigned)(unsigned short)f2bf(lo);
}

__device__ __forceinline__ void gl_lds16(const void* g, void* l) {
  __builtin_amdgcn_global_load_lds(
      (const __attribute__((address_space(1))) unsigned int*)g,
      (__attribute__((address_space(3))) unsigned int*)l, 16, 0, 0);
}

__device__ __forceinline__ f32x4 mfma_bf16(short8 a, short8 b, f32x4 c) {
  return __builtin_amdgcn_mfma_f32_16x16x32_bf16(
      __builtin_bit_cast(bf16x8, a), __builtin_bit_cast(bf16x8, b), c, 0, 0, 0);
}

__device__ __forceinline__ float2 sw16f(float x) {
  float a = x, bv;
  asm("v_mov_b32 %0, %1" : "=v"(bv) : "v"(x));
  asm("v_permlane16_swap_b32 %0, %1" : "+v"(a), "+v"(bv));
  return make_float2(a, bv);
}
__device__ __forceinline__ float2 sw32f(float x) {
  float a = x, bv;
  asm("v_mov_b32 %0, %1" : "=v"(bv) : "v"(x));
  asm("v_permlane32_swap_b32 %0, %1" : "+v"(a), "+v"(bv));
  return make_float2(a, bv);
}
__device__ __forceinline__ void sw16u(unsigned x, unsigned& e, unsigned& o) {
  unsigned a = x, bv;
  asm("v_mov_b32 %0, %1" : "=v"(bv) : "v"(x));
  asm("v_permlane16_swap_b32 %0, %1" : "+v"(a), "+v"(bv));
  e = a; o = bv;
}
__device__ __forceinline__ void pl32u(unsigned& a, unsigned& b) {
  asm("v_permlane32_swap_b32 %0, %1" : "+v"(a), "+v"(b));
}

// ---------------- cast x -> bf16 ----------------
__global__ void cast_f32_bf16(const float* __restrict__ in, short* __restrict__ out, int n4) {
  int i = blockIdx.x * blockDim.x + threadIdx.x;
  int stride = gridDim.x * blockDim.x;
  for (; i < n4; i += stride) {
    float4 v = ((const float4*)in)[i];
    short4 s;
    s.x = f2bf(v.x); s.y = f2bf(v.y); s.z = f2bf(v.z); s.w = f2bf(v.w);
    ((short4*)out)[i] = s;
  }
}

// ---------------- 4x W (K,N) f32 -> Wt (N,K) bf16, fused ----------------
__global__ void transpose_cast_w4(const float* __restrict__ Wq, const float* __restrict__ Wk,
                                  const float* __restrict__ Wv, const float* __restrict__ Wo,
                                  short* __restrict__ wqkv, short* __restrict__ wo) {
  __shared__ float t[32][33];
  int z = blockIdx.z;
  const float* W = z == 0 ? Wq : z == 1 ? Wk : z == 2 ? Wv : Wo;
  short* dst = z < 3 ? wqkv + (size_t)z * D_ * D_ : wo;
  int n0 = blockIdx.x * 32, k0 = blockIdx.y * 32;
  int tx = threadIdx.x, ty = threadIdx.y;
#pragma unroll
  for (int j = 0; j < 4; ++j)
    t[ty + j * 8][tx] = W[(size_t)(k0 + ty + j * 8) * D_ + n0 + tx];
  __syncthreads();
#pragma unroll
  for (int j = 0; j < 4; ++j)
    dst[(size_t)(n0 + ty + j * 8) * D_ + k0 + tx] = f2bf(t[tx][ty + j * 8]);
}

// ---------------- v (bh,T,HD) bf16 -> vt (bh,HD,T) bf16 ----------------
__global__ void transpose_v(const short* __restrict__ vb, short* __restrict__ vtb) {
  __shared__ short t[32][33];
  int bh = blockIdx.z;
  int t0 = blockIdx.x * 32, h0 = blockIdx.y * 32;
  int tx = threadIdx.x, ty = threadIdx.y;
  const short* src = vb + (size_t)bh * T_ * HD_;
  short* dst = vtb + (size_t)bh * HD_ * T_;
#pragma unroll
  for (int j = 0; j < 4; ++j)
    t[ty + j * 8][tx] = src[(size_t)(t0 + ty + j * 8) * HD_ + h0 + tx];
  __syncthreads();
#pragma unroll
  for (int j = 0; j < 4; ++j)
    dst[(size_t)(h0 + ty + j * 8) * T_ + t0 + tx] = t[tx][ty + j * 8];
}

// ---------------- ring-4 GEMM: C(M,Nt) = A(M,K) * Bt(Nt,K), 128x128 tile ----------------
// 4 LDS slots (64 KB), stage tile t+3 while computing tile t, counted vmcnt(8),
// raw s_barrier (no vmcnt(0) drain in loop). Slots compile-time via 4x unroll.
// MODE 0: fused QKV epilogue (Nt=6144: region q/k/v, split-head bf16 + k/v f32)
// MODE 1: plain f32 row-major out (Nt=2048)
template <int MODE>
__global__ __launch_bounds__(256, 2) void gemm_rb(
    const short* __restrict__ A, const short* __restrict__ Bt,
    const float* __restrict__ b0, const float* __restrict__ b1,
    const float* __restrict__ b2,
    short* __restrict__ q_o, short* __restrict__ k_o, short* __restrict__ v_o,
    float* __restrict__ kf_o, float* __restrict__ vf_o, float* __restrict__ f_o) {
  __shared__ __attribute__((aligned(16))) short lds[4][2][4096];  // 64 KB
  const int K = D_, NT = K / 32;

  int nx = gridDim.x, nwg = nx * gridDim.y;
  int d = blockIdx.y * nx + blockIdx.x;
  int cpx = nwg >> 3;
  int lg = (d & 7) * cpx + (d >> 3);
  int m0 = (lg / nx) * 128, n0 = (lg % nx) * 128;

  int tid = threadIdx.x, lane = tid & 63, w = tid >> 6;
  int wm = w >> 1, wn = w & 1;
  int lr = lane & 15, g = lane >> 4;

  // staging: thread covers LDS bytes o1,o2 of each 8KB tile (rows of 64B,
  // XOR-swizzle ((row>>1)&3)<<4 applied to the *global source*, rule #21)
  int o1 = tid * 16, o2 = 4096 + tid * 16;
  int row1 = tid >> 2, row2 = 64 + row1;
  int cb = (tid & 3) << 4;
  int c1 = (cb ^ (((row1 >> 1) & 3) << 4)) >> 1;
  int c2 = (cb ^ (((row2 >> 1) & 3) << 4)) >> 1;
  const short* aS1 = A + (size_t)(m0 + row1) * K + c1;
  const short* aS2 = A + (size_t)(m0 + row2) * K + c2;
  const short* bS1 = Bt + (size_t)(n0 + row1) * K + c1;
  const short* bS2 = Bt + (size_t)(n0 + row2) * K + c2;

  int aoff[4], boff[4];
#pragma unroll
  for (int i = 0; i < 4; ++i) {
    int ra = wm * 64 + i * 16 + lr;
    aoff[i] = ra * 64 + ((g * 16) ^ (((ra >> 1) & 3) << 4));
    int rb = wn * 64 + i * 16 + lr;
    boff[i] = rb * 64 + ((g * 16) ^ (((rb >> 1) & 3) << 4));
  }

  f32x4 acc[4][4] = {};

  // prologue: stage tiles 0,1,2 into slots 0,1,2
#pragma unroll
  for (int s = 0; s < 3; ++s) {
    char* la = (char*)&lds[s][0][0];
    char* lb = (char*)&lds[s][1][0];
    gl_lds16(aS1 + s * 32, la + o1);
    gl_lds16(aS2 + s * 32, la + o2);
    gl_lds16(bS1 + s * 32, lb + o1);
    gl_lds16(bS2 + s * 32, lb + o2);
  }
  asm volatile("s_waitcnt vmcnt(8)" ::: "memory");
  __builtin_amdgcn_s_barrier();
  __builtin_amdgcn_sched_barrier(0);

#pragma unroll 1
  for (int t4 = 0; t4 < NT; t4 += 4) {
#pragma unroll
    for (int p = 0; p < 4; ++p) {
      int t = t4 + p;
      // stage tile t+3 (phantom re-stage of last tile at the tail) into slot (p+3)&3
      {
        int ts = (t + 3 < NT) ? t + 3 : NT - 1;
        char* la = (char*)&lds[(p + 3) & 3][0][0];
        char* lb = (char*)&lds[(p + 3) & 3][1][0];
        gl_lds16(aS1 + ts * 32, la + o1);
        gl_lds16(aS2 + ts * 32, la + o2);
        gl_lds16(bS1 + ts * 32, lb + o1);
        gl_lds16(bS2 + ts * 32, lb + o2);
      }
      const char* la = (const char*)&lds[p][0][0];
      const char* lb = (const char*)&lds[p][1][0];
      short8 af[4], bfv[4];
#pragma unroll
      for (int i = 0; i < 4; ++i) {
        af[i] = *(const short8*)(la + aoff[i]);
        bfv[i] = *(const short8*)(lb + boff[i]);
      }
      __builtin_amdgcn_s_setprio(1);
#pragma unroll
      for (int mi = 0; mi < 4; ++mi)
#pragma unroll
        for (int ni = 0; ni < 4; ++ni)
          acc[mi][ni] = mfma_bf16(af[mi], bfv[ni], acc[mi][ni]);
      __builtin_amdgcn_s_setprio(0);
      asm volatile("s_waitcnt vmcnt(8)" ::: "memory");
      __builtin_amdgcn_s_barrier();
      __builtin_amdgcn_sched_barrier(0);
    }
  }

  if (MODE == 0) {
    int region = n0 >> 11;
    int nc = n0 & 2047;
    const float* bias = region == 0 ? b0 : region == 1 ? b1 : b2;
    short* obf = region == 0 ? q_o : region == 1 ? k_o : v_o;
    float* of32 = region == 1 ? kf_o : region == 2 ? vf_o : nullptr;
#pragma unroll
    for (int mi = 0; mi < 4; ++mi) {
#pragma unroll
      for (int ni = 0; ni < 4; ++ni) {
        int gr0 = m0 + wm * 64 + mi * 16 + (g << 2);
        int gc = nc + wn * 64 + ni * 16 + lr;
        float bv = bias[gc];
#pragma unroll
        for (int r = 0; r < 4; ++r) {
          int gr = gr0 + r;
          float v = acc[mi][ni][r] + bv;
          int bb = gr >> 11, tt = gr & (T_ - 1), hh = gc >> 7, hd = gc & (HD_ - 1);
          size_t idx = (((size_t)(bb * H_ + hh) * T_) + tt) * HD_ + hd;
          obf[idx] = f2bf(v);
          if (of32) of32[idx] = v;
        }
      }
    }
  } else {
#pragma unroll
    for (int mi = 0; mi < 4; ++mi) {
#pragma unroll
      for (int ni = 0; ni < 4; ++ni) {
        int gr0 = m0 + wm * 64 + mi * 16 + (g << 2);
        int gc = n0 + wn * 64 + ni * 16 + lr;
        float bv = b0[gc];
#pragma unroll
        for (int r = 0; r < 4; ++r)
          f_o[(size_t)(gr0 + r) * D_ + gc] = acc[mi][ni][r] + bv;
      }
    }
  }
}

// ---------------- causal flash attention (v5) ----------------
__global__ __launch_bounds__(256, 2) void attn_fwd(
    const short* __restrict__ qb, const short* __restrict__ kb,
    const short* __restrict__ vtb, short* __restrict__ aob) {
  __shared__ __attribute__((aligned(16))) char kvlds[2][16384];  // [buf]: K 8K | V 8K

  int d = blockIdx.y * gridDim.x + blockIdx.x;
  int lg = (d & 7) * 64 + (d >> 3);
  int bh = lg >> 4, jx = lg & 15;

  int tid = threadIdx.x, w = tid >> 6, lane = tid & 63;
  int lr = lane & 15, g = lane >> 4;
  const short* Q  = qb  + (size_t)bh * T_ * HD_;
  const short* Kp = kb  + (size_t)bh * T_ * HD_;
  const short* Vt = vtb + (size_t)bh * HD_ * T_;
  const float scale = 0.08838834764831845f;
  int b = bh >> 4, h = bh & 15;
  bool hi16 = (lane & 16) != 0;

  int oA = ((2 * w + 0) * 64 + lane) * 16;
  int oB = ((2 * w + 1) * 64 + lane) * 16;
  int rKA = oA >> 8, rKB = oB >> 8;
  size_t skA = (size_t)rKA * HD_ + (((oA & 255) ^ ((rKA & 7) << 4)) >> 1);
  size_t skB = (size_t)rKB * HD_ + (((oB & 255) ^ ((rKB & 7) << 4)) >> 1);
  int rVA = oA >> 6, rVB = oB >> 6;
  size_t svA = (size_t)rVA * T_ + (((oA & 63) ^ (((rVA >> 1) & 3) << 4)) >> 1);
  size_t svB = (size_t)rVB * T_ + (((oB & 63) ^ (((rVB >> 1) & 3) << 4)) >> 1);

#pragma unroll 1
  for (int pass = 0; pass < 2; ++pass) {
    int qt = pass ? (31 - jx) : jx;
    int q0 = qt * 64 + w * 16;
    int ntiles = 2 * qt + 2;

    {
      char* kd = &kvlds[0][0];
      char* vd = &kvlds[0][8192];
      gl_lds16(Kp + skA, kd + oA);
      gl_lds16(Kp + skB, kd + oB);
      gl_lds16(Vt + svA, vd + oA);
      gl_lds16(Vt + svB, vd + oB);
    }

    short8 qf[4];
#pragma unroll
    for (int kk = 0; kk < 4; ++kk)
      qf[kk] = *(const short8*)&Q[(size_t)(q0 + lr) * HD_ + kk * 32 + g * 8];

    f32x4 o[8] = {};
    float mrow = -1e30f, lrow = 0.f;
    __syncthreads();

#pragma unroll 1
    for (int t = 0; t < ntiles; ++t) {
      int kv0 = t * 32, buf = t & 1;
      if (t + 1 < ntiles) {
        char* kd = &kvlds[buf ^ 1][0];
        char* vd = &kvlds[buf ^ 1][8192];
        const short* Kn = Kp + (size_t)(kv0 + 32) * HD_;
        const short* Vn = Vt + (kv0 + 32);
        gl_lds16(Kn + skA, kd + oA);
        gl_lds16(Kn + skB, kd + oB);
        gl_lds16(Vn + svA, vd + oA);
        gl_lds16(Vn + svB, vd + oB);
      }
      if (kv0 < q0 + 16) {
        const char* kb_ = &kvlds[buf][0];
        const char* vb_ = &kvlds[buf][8192];
        short8 kf0[4], kf1[4], vf[8];
#pragma unroll
        for (int kk = 0; kk < 4; ++kk) {
          int cs = (kk * 64 + g * 16) ^ ((lr & 7) << 4);
          kf0[kk] = *(const short8*)(kb_ + (lr * 256 + cs));
          kf1[kk] = *(const short8*)(kb_ + ((16 + lr) * 256 + cs));
        }
#pragma unroll
        for (int f = 0; f < 8; ++f)
          vf[f] = *(const short8*)(vb_ + ((f * 16 + lr) * 64 +
                   ((g * 16) ^ (((lr >> 1) & 3) << 4))));

        f32x4 s0 = {}, s1 = {};
        __builtin_amdgcn_s_setprio(1);
#pragma unroll
        for (int kk = 0; kk < 4; ++kk) {
          s0 = mfma_bf16(kf0[kk], qf[kk], s0);
          s1 = mfma_bf16(kf1[kk], qf[kk], s1);
        }
        __builtin_amdgcn_s_setprio(0);

        float vv[8];
#pragma unroll
        for (int r = 0; r < 4; ++r) {
          vv[r] = s0[r] * scale;
          vv[4 + r] = s1[r] * scale;
        }
        if (kv0 + 31 > q0) {
          int qrow = q0 + lr;
#pragma unroll
          for (int r = 0; r < 4; ++r) {
            if (kv0 + 4 * g + r > qrow) vv[r] = -1e30f;
            if (kv0 + 16 + 4 * g + r > qrow) vv[4 + r] = -1e30f;
          }
        }

        float pm = vv[0];
#pragma unroll
        for (int i = 1; i < 8; ++i) pm = fmaxf(pm, vv[i]);
        { float2 tpm = sw32f(pm); pm = fmaxf(tpm.x, tpm.y); }
        { float2 tpm = sw16f(pm); pm = fmaxf(tpm.x, tpm.y); }

        bool rescale = !__all(pm - mrow <= 8.0f);
        float alpha = 1.0f;
        if (rescale) {
          float mnew = fmaxf(mrow, pm);
          alpha = __expf(mrow - mnew);
          mrow = mnew;
        }

        float p[8];
        float rs = 0.f;
#pragma unroll
        for (int i = 0; i < 8; ++i) { p[i] = __expf(vv[i] - mrow); rs += p[i]; }
        { float2 trs = sw32f(rs); rs = trs.x + trs.y; }
        { float2 trs = sw16f(rs); rs = trs.x + trs.y; }
        lrow = (rescale ? lrow * alpha : lrow) + rs;

        if (rescale) {
          float alr[4];
#pragma unroll
          for (int r = 0; r < 4; ++r) alr[r] = __shfl(alpha, 4 * g + r);
#pragma unroll
          for (int f = 0; f < 8; ++f)
#pragma unroll
            for (int r = 0; r < 4; ++r) o[f][r] *= alr[r];
        }

        unsigned w0 = pk2(p[0], p[1]), w1 = pk2(p[2], p[3]);
        unsigned w2 = pk2(p[4], p[5]), w3 = pk2(p[6], p[7]);
        unsigned e0, od0, e1, od1, e2, od2, e3, od3;
        sw16u(w0, e0, od0); sw16u(w1, e1, od1);
        sw16u(w2, e2, od2); sw16u(w3, e3, od3);
        unsigned F0 = e0,  S0 = e2;  pl32u(F0, S0);
        unsigned F1 = e1,  S1 = e3;  pl32u(F1, S1);
        unsigned F2 = od0, S2 = od2; pl32u(F2, S2);
        unsigned F3 = od1, S3 = od3; pl32u(F3, S3);
        uint32x4 paw = { hi16 ? S0 : F0, hi16 ? S1 : F1,
                         hi16 ? S2 : F2, hi16 ? S3 : F3 };
        short8 pa = __builtin_bit_cast(short8, paw);

        __builtin_amdgcn_s_setprio(1);
#pragma unroll
        for (int f = 0; f < 8; ++f) o[f] = mfma_bf16(pa, vf[f], o[f]);
        __builtin_amdgcn_s_setprio(0);
      }
      __syncthreads();
    }

    float inv = 1.0f / lrow;
    float invr[4];
#pragma unroll
    for (int r = 0; r < 4; ++r) invr[r] = __shfl(inv, 4 * g + r);
#pragma unroll
    for (int r = 0; r < 4; ++r) {
      int q = q0 + 4 * g + r;
      size_t rowoff = ((size_t)(b * T_ + q)) * D_ + h * HD_;
#pragma unroll
      for (int f = 0; f < 8; ++f)
        aob[rowoff + f * 16 + lr] = f2bf(o[f][r] * invr[r]);
    }
  }
}

extern "C" void kernel_launch(void* const* d_in, const int* in_sizes, int n_in,
                              void* d_out, int out_size, void* d_ws, size_t ws_size,
                              hipStream_t stream) {
  const float* x  = (const float*)d_in[0];
  const float* Wq = (const float*)d_in[1];
  const float* bq = (const float*)d_in[2];
  const float* Wk = (const float*)d_in[3];
  const float* bk = (const float*)d_in[4];
  const float* Wv = (const float*)d_in[5];
  const float* bv = (const float*)d_in[6];
  const float* Wo = (const float*)d_in[7];
  const float* bo = (const float*)d_in[8];
  float* out  = (float*)d_out;
  float* kout = out + (size_t)M_ * D_;
  float* vout = kout + (size_t)M_ * D_;

  char* ws = (char*)d_ws;
  auto alloc = [&](size_t bytes) {
    char* p = ws;
    ws += (bytes + 255) & ~(size_t)255;
    return p;
  };
  short* xb    = (short*)alloc((size_t)M_ * D_ * 2);
  short* wqkvT = (short*)alloc((size_t)3 * D_ * D_ * 2);
  short* woT   = (short*)alloc((size_t)D_ * D_ * 2);
  short* qb    = (short*)alloc((size_t)M_ * D_ * 2);
  short* kb    = (short*)alloc((size_t)M_ * D_ * 2);
  short* vb    = (short*)alloc((size_t)M_ * D_ * 2);
  short* vtb = wqkvT;  // reuse: wqkvT dead after QKV GEMM
  short* aob = xb;     // reuse: xb dead after QKV GEMM

  cast_f32_bf16<<<2048, 256, 0, stream>>>(x, xb, M_ * D_ / 4);
  dim3 tb(32, 8);
  transpose_cast_w4<<<dim3(64, 64, 4), tb, 0, stream>>>(Wq, Wk, Wv, Wo, wqkvT, woT);

  gemm_rb<0><<<dim3(48, 32), 256, 0, stream>>>(
      xb, wqkvT, bq, bk, bv, qb, kb, vb, kout, vout, nullptr);
  transpose_v<<<dim3(T_ / 32, HD_ / 32, B_ * H_), tb, 0, stream>>>(vb, vtb);
  attn_fwd<<<dim3(16, 32), 256, 0, stream>>>(qb, kb, vtb, aob);
  gemm_rb<1><<<dim3(16, 32), 256, 0, stream>>>(
      aob, woT, bo, nullptr, nullptr, nullptr, nullptr, nullptr,
      nullptr, nullptr, out);
}

// Round 6
// 275.274 us; speedup vs baseline: 2.6322x; 1.0660x over previous
//
#include <hip/hip_runtime.h>
#include <hip/hip_bf16.h>

#define B_ 2
#define T_ 2048
#define D_ 2048
#define H_ 16
#define HD_ 128
#define M_ 4096

typedef __attribute__((ext_vector_type(8))) short short8;
typedef __attribute__((ext_vector_type(8))) __bf16 bf16x8;
typedef __attribute__((ext_vector_type(4))) float f32x4;
typedef __attribute__((ext_vector_type(4))) unsigned uint32x4;

__device__ __forceinline__ short f2bf(float f) {
  unsigned u = __builtin_bit_cast(unsigned, f);
  u += 0x7fffu + ((u >> 16) & 1u);
  return (short)(u >> 16);
}

__device__ __forceinline__ unsigned pk2(float lo, float hi) {
  return ((unsigned)(unsigned short)f2bf(hi) << 16) |
         (unsigned)(unsigned short)f2bf(lo);
}

__device__ __forceinline__ void gl_lds16(const void* g, void* l) {
  __builtin_amdgcn_global_load_lds(
      (const __attribute__((address_space(1))) unsigned int*)g,
      (__attribute__((address_space(3))) unsigned int*)l, 16, 0, 0);
}

__device__ __forceinline__ f32x4 mfma_bf16(short8 a, short8 b, f32x4 c) {
  return __builtin_amdgcn_mfma_f32_16x16x32_bf16(
      __builtin_bit_cast(bf16x8, a), __builtin_bit_cast(bf16x8, b), c, 0, 0, 0);
}

__device__ __forceinline__ float2 sw16f(float x) {
  float a = x, bv;
  asm("v_mov_b32 %0, %1" : "=v"(bv) : "v"(x));
  asm("v_permlane16_swap_b32 %0, %1" : "+v"(a), "+v"(bv));
  return make_float2(a, bv);
}
__device__ __forceinline__ float2 sw32f(float x) {
  float a = x, bv;
  asm("v_mov_b32 %0, %1" : "=v"(bv) : "v"(x));
  asm("v_permlane32_swap_b32 %0, %1" : "+v"(a), "+v"(bv));
  return make_float2(a, bv);
}
__device__ __forceinline__ void sw16u(unsigned x, unsigned& e, unsigned& o) {
  unsigned a = x, bv;
  asm("v_mov_b32 %0, %1" : "=v"(bv) : "v"(x));
  asm("v_permlane16_swap_b32 %0, %1" : "+v"(a), "+v"(bv));
  e = a; o = bv;
}
__device__ __forceinline__ void pl32u(unsigned& a, unsigned& b) {
  asm("v_permlane32_swap_b32 %0, %1" : "+v"(a), "+v"(b));
}

// ---------------- cast x -> bf16 ----------------
__global__ void cast_f32_bf16(const float* __restrict__ in, short* __restrict__ out, int n4) {
  int i = blockIdx.x * blockDim.x + threadIdx.x;
  int stride = gridDim.x * blockDim.x;
  for (; i < n4; i += stride) {
    float4 v = ((const float4*)in)[i];
    short4 s;
    s.x = f2bf(v.x); s.y = f2bf(v.y); s.z = f2bf(v.z); s.w = f2bf(v.w);
    ((short4*)out)[i] = s;
  }
}

// ---------------- 4x W (K,N) f32 -> Wt (N,K) bf16, fused ----------------
__global__ void transpose_cast_w4(const float* __restrict__ Wq, const float* __restrict__ Wk,
                                  const float* __restrict__ Wv, const float* __restrict__ Wo,
                                  short* __restrict__ wqkv, short* __restrict__ wo) {
  __shared__ float t[32][33];
  int z = blockIdx.z;
  const float* W = z == 0 ? Wq : z == 1 ? Wk : z == 2 ? Wv : Wo;
  short* dst = z < 3 ? wqkv + (size_t)z * D_ * D_ : wo;
  int n0 = blockIdx.x * 32, k0 = blockIdx.y * 32;
  int tx = threadIdx.x, ty = threadIdx.y;
#pragma unroll
  for (int j = 0; j < 4; ++j)
    t[ty + j * 8][tx] = W[(size_t)(k0 + ty + j * 8) * D_ + n0 + tx];
  __syncthreads();
#pragma unroll
  for (int j = 0; j < 4; ++j)
    dst[(size_t)(n0 + ty + j * 8) * D_ + k0 + tx] = f2bf(t[tx][ty + j * 8]);
}

// ---------------- v (bh,T,HD) bf16 -> vt (bh,HD,T) bf16 ----------------
__global__ void transpose_v(const short* __restrict__ vb, short* __restrict__ vtb) {
  __shared__ short t[32][33];
  int bh = blockIdx.z;
  int t0 = blockIdx.x * 32, h0 = blockIdx.y * 32;
  int tx = threadIdx.x, ty = threadIdx.y;
  const short* src = vb + (size_t)bh * T_ * HD_;
  short* dst = vtb + (size_t)bh * HD_ * T_;
#pragma unroll
  for (int j = 0; j < 4; ++j)
    t[ty + j * 8][tx] = src[(size_t)(t0 + ty + j * 8) * HD_ + h0 + tx];
  __syncthreads();
#pragma unroll
  for (int j = 0; j < 4; ++j)
    dst[(size_t)(h0 + ty + j * 8) * T_ + t0 + tx] = t[tx][ty + j * 8];
}

// ---------------- 256x256 deep-pipelined QKV GEMM ----------------
// 512 thr = 8 waves (2M x 4N), per-wave C = 128x64 (acc[8][4]). BK=64 as two
// 32-wide K-halves. LDS 128 KB: [buf][kh][mat] slots of [256][32] bf16, XOR
// swizzle byte^=((row&3)<<4) (staged via inverse-swizzled global source).
// 4 phases/K-tile: {ds_read subtile | stage 1 half (2 gl_lds) | 16 MFMA | bar}.
// Stage schedule: ph0->Bk1(t+1), ph1->Ak0(t+2), ph2->Bk0(t+2), ph3->Ak1(t+2);
// counted s_waitcnt vmcnt(10) at ph1/ph3 only (5 halves x 2 loads in flight).
__global__ __launch_bounds__(512, 2) void gemm_qkv(
    const short* __restrict__ A, const short* __restrict__ Bt,
    const float* __restrict__ b0, const float* __restrict__ b1,
    const float* __restrict__ b2,
    short* __restrict__ q_o, short* __restrict__ k_o, short* __restrict__ v_o,
    float* __restrict__ kf_o, float* __restrict__ vf_o) {
  __shared__ __attribute__((aligned(16))) short lds[2][2][2][8192];  // 128 KB
  const int K = D_, NT = K / 64, NX = 24;

  int d = blockIdx.x;
  int lg = (d & 7) * 48 + (d >> 3);          // 384 = 8 XCD x 48, bijective
  int m0 = (lg / NX) * 256, n0 = (lg % NX) * 256;

  int tid = threadIdx.x, lane = tid & 63, wid = tid >> 6;
  int wm = wid >> 2, wn = wid & 3;
  int lr = lane & 15, g = lane >> 4;

  // staging source (inverse swizzle on global col; (sr+128)&3 == sr&3)
  int sr = tid >> 2;
  int sc = (((tid & 3) << 4) ^ ((sr & 3) << 4)) >> 1;
  const short* aSrc = A + (size_t)(m0 + sr) * K + sc;
  const short* bSrc = Bt + (size_t)(n0 + sr) * K + sc;
  char* ldsb = (char*)lds;

  auto stage = [&](int ts, int kh, int mat) {
    char* dst = ldsb + ((((ts & 1) * 2 + kh) * 2 + mat) << 14) + tid * 16;
    const short* s = (mat == 0 ? aSrc : bSrc) + ts * 64 + kh * 32;
    gl_lds16(s, dst);
    gl_lds16(s + (size_t)128 * K, dst + 8192);
  };

  // frag read lane offsets (row&3 == lr&3 since 16 | other terms)
  int swz = (g * 16) ^ ((lr & 3) << 4);
  int aoffl = (wm * 128 + lr) * 64 + swz;
  int boffl = (wn * 64 + lr) * 64 + swz;

  f32x4 acc[8][4] = {};

  // prologue: 7 halves
  stage(0, 0, 0); stage(0, 0, 1); stage(0, 1, 0); stage(0, 1, 1);
  stage(1, 0, 0); stage(1, 0, 1); stage(1, 1, 0);
  asm volatile("s_waitcnt vmcnt(10)" ::: "memory");
  __builtin_amdgcn_s_barrier();
  __builtin_amdgcn_sched_barrier(0);

#pragma unroll 1
  for (int t = 0; t < NT; ++t) {
    const char* La = ldsb + (t & 1) * 65536 + aoffl;
    const char* Lb = ldsb + (t & 1) * 65536 + 16384 + boffl;
    int t1 = (t + 1 < NT) ? t + 1 : NT - 1;
    int t2 = (t + 2 < NT) ? t + 2 : NT - 1;
    short8 afr[8], bf0, bf1;

    // ---- ph0: k-half 0, ni 0-1 ----
#pragma unroll
    for (int mi = 0; mi < 8; ++mi) afr[mi] = *(const short8*)(La + mi * 1024);
    bf0 = *(const short8*)(Lb);
    bf1 = *(const short8*)(Lb + 1024);
    stage(t1, 1, 1);
    __builtin_amdgcn_s_setprio(1);
#pragma unroll
    for (int mi = 0; mi < 8; ++mi) {
      acc[mi][0] = mfma_bf16(afr[mi], bf0, acc[mi][0]);
      acc[mi][1] = mfma_bf16(afr[mi], bf1, acc[mi][1]);
    }
    __builtin_amdgcn_s_setprio(0);
    __builtin_amdgcn_s_barrier();
    __builtin_amdgcn_sched_barrier(0);

    // ---- ph1: k-half 0, ni 2-3 ----
    bf0 = *(const short8*)(Lb + 2048);
    bf1 = *(const short8*)(Lb + 3072);
    stage(t2, 0, 0);
    asm volatile("s_waitcnt vmcnt(10)" ::: "memory");
    __builtin_amdgcn_s_setprio(1);
#pragma unroll
    for (int mi = 0; mi < 8; ++mi) {
      acc[mi][2] = mfma_bf16(afr[mi], bf0, acc[mi][2]);
      acc[mi][3] = mfma_bf16(afr[mi], bf1, acc[mi][3]);
    }
    __builtin_amdgcn_s_setprio(0);
    __builtin_amdgcn_s_barrier();
    __builtin_amdgcn_sched_barrier(0);

    // ---- ph2: k-half 1, ni 0-1 ----
#pragma unroll
    for (int mi = 0; mi < 8; ++mi) afr[mi] = *(const short8*)(La + 32768 + mi * 1024);
    bf0 = *(const short8*)(Lb + 32768);
    bf1 = *(const short8*)(Lb + 32768 + 1024);
    stage(t2, 0, 1);
    __builtin_amdgcn_s_setprio(1);
#pragma unroll
    for (int mi = 0; mi < 8; ++mi) {
      acc[mi][0] = mfma_bf16(afr[mi], bf0, acc[mi][0]);
      acc[mi][1] = mfma_bf16(afr[mi], bf1, acc[mi][1]);
    }
    __builtin_amdgcn_s_setprio(0);
    __builtin_amdgcn_s_barrier();
    __builtin_amdgcn_sched_barrier(0);

    // ---- ph3: k-half 1, ni 2-3 ----
    bf0 = *(const short8*)(Lb + 32768 + 2048);
    bf1 = *(const short8*)(Lb + 32768 + 3072);
    stage(t2, 1, 0);
    asm volatile("s_waitcnt vmcnt(10)" ::: "memory");
    __builtin_amdgcn_s_setprio(1);
#pragma unroll
    for (int mi = 0; mi < 8; ++mi) {
      acc[mi][2] = mfma_bf16(afr[mi], bf0, acc[mi][2]);
      acc[mi][3] = mfma_bf16(afr[mi], bf1, acc[mi][3]);
    }
    __builtin_amdgcn_s_setprio(0);
    __builtin_amdgcn_s_barrier();
    __builtin_amdgcn_sched_barrier(0);
  }

  // epilogue: bias + split-head (BN=256 never spans q/k/v regions)
  int region = n0 >> 11, nc = n0 & 2047;
  const float* bias = region == 0 ? b0 : region == 1 ? b1 : b2;
  short* obf = region == 0 ? q_o : region == 1 ? k_o : v_o;
  float* of32 = region == 1 ? kf_o : region == 2 ? vf_o : nullptr;
#pragma unroll
  for (int mi = 0; mi < 8; ++mi) {
#pragma unroll
    for (int ni = 0; ni < 4; ++ni) {
      int gr0 = m0 + wm * 128 + mi * 16 + (g << 2);
      int gc = nc + wn * 64 + ni * 16 + lr;
      float bv = bias[gc];
#pragma unroll
      for (int r = 0; r < 4; ++r) {
        int gr = gr0 + r;
        float v = acc[mi][ni][r] + bv;
        int bb = gr >> 11, tt = gr & (T_ - 1), hh = gc >> 7, hd = gc & (HD_ - 1);
        size_t idx = (((size_t)(bb * H_ + hh) * T_) + tt) * HD_ + hd;
        obf[idx] = f2bf(v);
        if (of32) of32[idx] = v;
      }
    }
  }
}

// ---------------- ring-4 GEMM (Wo): C(M,2048) = A * Bt + bias, f32 out ----------------
__global__ __launch_bounds__(256, 2) void gemm_rb(
    const short* __restrict__ A, const short* __restrict__ Bt,
    const float* __restrict__ b0, float* __restrict__ f_o) {
  __shared__ __attribute__((aligned(16))) short lds[4][2][4096];
  const int K = D_, NT = K / 32;

  int nx = gridDim.x, nwg = nx * gridDim.y;
  int d = blockIdx.y * nx + blockIdx.x;
  int cpx = nwg >> 3;
  int lg = (d & 7) * cpx + (d >> 3);
  int m0 = (lg / nx) * 128, n0 = (lg % nx) * 128;

  int tid = threadIdx.x, lane = tid & 63, w = tid >> 6;
  int wm = w >> 1, wn = w & 1;
  int lr = lane & 15, g = lane >> 4;

  int o1 = tid * 16, o2 = 4096 + tid * 16;
  int row1 = tid >> 2, row2 = 64 + row1;
  int cb = (tid & 3) << 4;
  int c1 = (cb ^ (((row1 >> 1) & 3) << 4)) >> 1;
  int c2 = (cb ^ (((row2 >> 1) & 3) << 4)) >> 1;
  const short* aS1 = A + (size_t)(m0 + row1) * K + c1;
  const short* aS2 = A + (size_t)(m0 + row2) * K + c2;
  const short* bS1 = Bt + (size_t)(n0 + row1) * K + c1;
  const short* bS2 = Bt + (size_t)(n0 + row2) * K + c2;

  int aoff[4], boff[4];
#pragma unroll
  for (int i = 0; i < 4; ++i) {
    int ra = wm * 64 + i * 16 + lr;
    aoff[i] = ra * 64 + ((g * 16) ^ (((ra >> 1) & 3) << 4));
    int rb = wn * 64 + i * 16 + lr;
    boff[i] = rb * 64 + ((g * 16) ^ (((rb >> 1) & 3) << 4));
  }

  f32x4 acc[4][4] = {};

#pragma unroll
  for (int s = 0; s < 3; ++s) {
    char* la = (char*)&lds[s][0][0];
    char* lb = (char*)&lds[s][1][0];
    gl_lds16(aS1 + s * 32, la + o1);
    gl_lds16(aS2 + s * 32, la + o2);
    gl_lds16(bS1 + s * 32, lb + o1);
    gl_lds16(bS2 + s * 32, lb + o2);
  }
  asm volatile("s_waitcnt vmcnt(8)" ::: "memory");
  __builtin_amdgcn_s_barrier();
  __builtin_amdgcn_sched_barrier(0);

#pragma unroll 1
  for (int t4 = 0; t4 < NT; t4 += 4) {
#pragma unroll
    for (int p = 0; p < 4; ++p) {
      int t = t4 + p;
      {
        int ts = (t + 3 < NT) ? t + 3 : NT - 1;
        char* la = (char*)&lds[(p + 3) & 3][0][0];
        char* lb = (char*)&lds[(p + 3) & 3][1][0];
        gl_lds16(aS1 + ts * 32, la + o1);
        gl_lds16(aS2 + ts * 32, la + o2);
        gl_lds16(bS1 + ts * 32, lb + o1);
        gl_lds16(bS2 + ts * 32, lb + o2);
      }
      const char* la = (const char*)&lds[p][0][0];
      const char* lb = (const char*)&lds[p][1][0];
      short8 af[4], bfv[4];
#pragma unroll
      for (int i = 0; i < 4; ++i) {
        af[i] = *(const short8*)(la + aoff[i]);
        bfv[i] = *(const short8*)(lb + boff[i]);
      }
      __builtin_amdgcn_s_setprio(1);
#pragma unroll
      for (int mi = 0; mi < 4; ++mi)
#pragma unroll
        for (int ni = 0; ni < 4; ++ni)
          acc[mi][ni] = mfma_bf16(af[mi], bfv[ni], acc[mi][ni]);
      __builtin_amdgcn_s_setprio(0);
      asm volatile("s_waitcnt vmcnt(8)" ::: "memory");
      __builtin_amdgcn_s_barrier();
      __builtin_amdgcn_sched_barrier(0);
    }
  }

#pragma unroll
  for (int mi = 0; mi < 4; ++mi) {
#pragma unroll
    for (int ni = 0; ni < 4; ++ni) {
      int gr0 = m0 + wm * 64 + mi * 16 + (g << 2);
      int gc = n0 + wn * 64 + ni * 16 + lr;
      float bv = b0[gc];
#pragma unroll
      for (int r = 0; r < 4; ++r)
        f_o[(size_t)(gr0 + r) * D_ + gc] = acc[mi][ni][r] + bv;
    }
  }
}

// ---------------- causal flash attention (v5) ----------------
__global__ __launch_bounds__(256, 2) void attn_fwd(
    const short* __restrict__ qb, const short* __restrict__ kb,
    const short* __restrict__ vtb, short* __restrict__ aob) {
  __shared__ __attribute__((aligned(16))) char kvlds[2][16384];

  int d = blockIdx.y * gridDim.x + blockIdx.x;
  int lg = (d & 7) * 64 + (d >> 3);
  int bh = lg >> 4, jx = lg & 15;

  int tid = threadIdx.x, w = tid >> 6, lane = tid & 63;
  int lr = lane & 15, g = lane >> 4;
  const short* Q  = qb  + (size_t)bh * T_ * HD_;
  const short* Kp = kb  + (size_t)bh * T_ * HD_;
  const short* Vt = vtb + (size_t)bh * HD_ * T_;
  const float scale = 0.08838834764831845f;
  int b = bh >> 4, h = bh & 15;
  bool hi16 = (lane & 16) != 0;

  int oA = ((2 * w + 0) * 64 + lane) * 16;
  int oB = ((2 * w + 1) * 64 + lane) * 16;
  int rKA = oA >> 8, rKB = oB >> 8;
  size_t skA = (size_t)rKA * HD_ + (((oA & 255) ^ ((rKA & 7) << 4)) >> 1);
  size_t skB = (size_t)rKB * HD_ + (((oB & 255) ^ ((rKB & 7) << 4)) >> 1);
  int rVA = oA >> 6, rVB = oB >> 6;
  size_t svA = (size_t)rVA * T_ + (((oA & 63) ^ (((rVA >> 1) & 3) << 4)) >> 1);
  size_t svB = (size_t)rVB * T_ + (((oB & 63) ^ (((rVB >> 1) & 3) << 4)) >> 1);

#pragma unroll 1
  for (int pass = 0; pass < 2; ++pass) {
    int qt = pass ? (31 - jx) : jx;
    int q0 = qt * 64 + w * 16;
    int ntiles = 2 * qt + 2;

    {
      char* kd = &kvlds[0][0];
      char* vd = &kvlds[0][8192];
      gl_lds16(Kp + skA, kd + oA);
      gl_lds16(Kp + skB, kd + oB);
      gl_lds16(Vt + svA, vd + oA);
      gl_lds16(Vt + svB, vd + oB);
    }

    short8 qf[4];
#pragma unroll
    for (int kk = 0; kk < 4; ++kk)
      qf[kk] = *(const short8*)&Q[(size_t)(q0 + lr) * HD_ + kk * 32 + g * 8];

    f32x4 o[8] = {};
    float mrow = -1e30f, lrow = 0.f;
    __syncthreads();

#pragma unroll 1
    for (int t = 0; t < ntiles; ++t) {
      int kv0 = t * 32, buf = t & 1;
      if (t + 1 < ntiles) {
        char* kd = &kvlds[buf ^ 1][0];
        char* vd = &kvlds[buf ^ 1][8192];
        const short* Kn = Kp + (size_t)(kv0 + 32) * HD_;
        const short* Vn = Vt + (kv0 + 32);
        gl_lds16(Kn + skA, kd + oA);
        gl_lds16(Kn + skB, kd + oB);
        gl_lds16(Vn + svA, vd + oA);
        gl_lds16(Vn + svB, vd + oB);
      }
      if (kv0 < q0 + 16) {
        const char* kb_ = &kvlds[buf][0];
        const char* vb_ = &kvlds[buf][8192];
        short8 kf0[4], kf1[4], vf[8];
#pragma unroll
        for (int kk = 0; kk < 4; ++kk) {
          int cs = (kk * 64 + g * 16) ^ ((lr & 7) << 4);
          kf0[kk] = *(const short8*)(kb_ + (lr * 256 + cs));
          kf1[kk] = *(const short8*)(kb_ + ((16 + lr) * 256 + cs));
        }
#pragma unroll
        for (int f = 0; f < 8; ++f)
          vf[f] = *(const short8*)(vb_ + ((f * 16 + lr) * 64 +
                   ((g * 16) ^ (((lr >> 1) & 3) << 4))));

        f32x4 s0 = {}, s1 = {};
        __builtin_amdgcn_s_setprio(1);
#pragma unroll
        for (int kk = 0; kk < 4; ++kk) {
          s0 = mfma_bf16(kf0[kk], qf[kk], s0);
          s1 = mfma_bf16(kf1[kk], qf[kk], s1);
        }
        __builtin_amdgcn_s_setprio(0);

        float vv[8];
#pragma unroll
        for (int r = 0; r < 4; ++r) {
          vv[r] = s0[r] * scale;
          vv[4 + r] = s1[r] * scale;
        }
        if (kv0 + 31 > q0) {
          int qrow = q0 + lr;
#pragma unroll
          for (int r = 0; r < 4; ++r) {
            if (kv0 + 4 * g + r > qrow) vv[r] = -1e30f;
            if (kv0 + 16 + 4 * g + r > qrow) vv[4 + r] = -1e30f;
          }
        }

        float pm = vv[0];
#pragma unroll
        for (int i = 1; i < 8; ++i) pm = fmaxf(pm, vv[i]);
        { float2 tpm = sw32f(pm); pm = fmaxf(tpm.x, tpm.y); }
        { float2 tpm = sw16f(pm); pm = fmaxf(tpm.x, tpm.y); }

        bool rescale = !__all(pm - mrow <= 8.0f);
        float alpha = 1.0f;
        if (rescale) {
          float mnew = fmaxf(mrow, pm);
          alpha = __expf(mrow - mnew);
          mrow = mnew;
        }

        float p[8];
        float rs = 0.f;
#pragma unroll
        for (int i = 0; i < 8; ++i) { p[i] = __expf(vv[i] - mrow); rs += p[i]; }
        { float2 trs = sw32f(rs); rs = trs.x + trs.y; }
        { float2 trs = sw16f(rs); rs = trs.x + trs.y; }
        lrow = (rescale ? lrow * alpha : lrow) + rs;

        if (rescale) {
          float alr[4];
#pragma unroll
          for (int r = 0; r < 4; ++r) alr[r] = __shfl(alpha, 4 * g + r);
#pragma unroll
          for (int f = 0; f < 8; ++f)
#pragma unroll
            for (int r = 0; r < 4; ++r) o[f][r] *= alr[r];
        }

        unsigned w0 = pk2(p[0], p[1]), w1 = pk2(p[2], p[3]);
        unsigned w2 = pk2(p[4], p[5]), w3 = pk2(p[6], p[7]);
        unsigned e0, od0, e1, od1, e2, od2, e3, od3;
        sw16u(w0, e0, od0); sw16u(w1, e1, od1);
        sw16u(w2, e2, od2); sw16u(w3, e3, od3);
        unsigned F0 = e0,  S0 = e2;  pl32u(F0, S0);
        unsigned F1 = e1,  S1 = e3;  pl32u(F1, S1);
        unsigned F2 = od0, S2 = od2; pl32u(F2, S2);
        unsigned F3 = od1, S3 = od3; pl32u(F3, S3);
        uint32x4 paw = { hi16 ? S0 : F0, hi16 ? S1 : F1,
                         hi16 ? S2 : F2, hi16 ? S3 : F3 };
        short8 pa = __builtin_bit_cast(short8, paw);

        __builtin_amdgcn_s_setprio(1);
#pragma unroll
        for (int f = 0; f < 8; ++f) o[f] = mfma_bf16(pa, vf[f], o[f]);
        __builtin_amdgcn_s_setprio(0);
      }
      __syncthreads();
    }

    float inv = 1.0f / lrow;
    float invr[4];
#pragma unroll
    for (int r = 0; r < 4; ++r) invr[r] = __shfl(inv, 4 * g + r);
#pragma unroll
    for (int r = 0; r < 4; ++r) {
      int q = q0 + 4 * g + r;
      size_t rowoff = ((size_t)(b * T_ + q)) * D_ + h * HD_;
#pragma unroll
      for (int f = 0; f < 8; ++f)
        aob[rowoff + f * 16 + lr] = f2bf(o[f][r] * invr[r]);
    }
  }
}

extern "C" void kernel_launch(void* const* d_in, const int* in_sizes, int n_in,
                              void* d_out, int out_size, void* d_ws, size_t ws_size,
                              hipStream_t stream) {
  const float* x  = (const float*)d_in[0];
  const float* Wq = (const float*)d_in[1];
  const float* bq = (const float*)d_in[2];
  const float* Wk = (const float*)d_in[3];
  const float* bk = (const float*)d_in[4];
  const float* Wv = (const float*)d_in[5];
  const float* bv = (const float*)d_in[6];
  const float* Wo = (const float*)d_in[7];
  const float* bo = (const float*)d_in[8];
  float* out  = (float*)d_out;
  float* kout = out + (size_t)M_ * D_;
  float* vout = kout + (size_t)M_ * D_;

  char* ws = (char*)d_ws;
  auto alloc = [&](size_t bytes) {
    char* p = ws;
    ws += (bytes + 255) & ~(size_t)255;
    return p;
  };
  short* xb    = (short*)alloc((size_t)M_ * D_ * 2);
  short* wqkvT = (short*)alloc((size_t)3 * D_ * D_ * 2);
  short* woT   = (short*)alloc((size_t)D_ * D_ * 2);
  short* qb    = (short*)alloc((size_t)M_ * D_ * 2);
  short* kb    = (short*)alloc((size_t)M_ * D_ * 2);
  short* vb    = (short*)alloc((size_t)M_ * D_ * 2);
  short* vtb = wqkvT;  // reuse: wqkvT dead after QKV GEMM
  short* aob = xb;     // reuse: xb dead after QKV GEMM

  cast_f32_bf16<<<2048, 256, 0, stream>>>(x, xb, M_ * D_ / 4);
  dim3 tb(32, 8);
  transpose_cast_w4<<<dim3(64, 64, 4), tb, 0, stream>>>(Wq, Wk, Wv, Wo, wqkvT, woT);

  gemm_qkv<<<384, 512, 0, stream>>>(xb, wqkvT, bq, bk, bv, qb, kb, vb, kout, vout);
  transpose_v<<<dim3(T_ / 32, HD_ / 32, B_ * H_), tb, 0, stream>>>(vb, vtb);
  attn_fwd<<<dim3(16, 32), 256, 0, stream>>>(qb, kb, vtb, aob);
  gemm_rb<<<dim3(16, 32), 256, 0, stream>>>(aob, woT, bo, out);
}